// Round 1
// baseline (1599.747 us; speedup 1.0000x reference)
//
#include <hip/hip_runtime.h>
#include <hip/hip_bf16.h>
#include <cmath>

#define BB 4
#define LL 2304
#define CC 768
#define DSTATE 16
#define DINNER 768
#define DTRANK 48
#define MTOK (BB*LL)          // 9216
#define NCH 16
#define LCH (LL/NCH)          // 144

typedef __bf16 bf16_t;
typedef __bf16 bf16x8 __attribute__((ext_vector_type(8)));
typedef float  f32x4  __attribute__((ext_vector_type(4)));

__device__ __forceinline__ float silu_f(float v){ return v / (1.0f + __expf(-v)); }

__device__ __forceinline__ bf16x8 bzero8(){
    bf16x8 v;
#pragma unroll
    for (int i=0;i<8;++i) v[i] = (bf16_t)0.0f;
    return v;
}

// ---------------- weight fp32 -> bf16 conversion (all 10 weight matrices) ----
__global__ __launch_bounds__(256)
void wconv_k(const float* __restrict__ a0, const float* __restrict__ a1,
             const float* __restrict__ a2, const float* __restrict__ a3,
             const float* __restrict__ a4, const float* __restrict__ a5,
             const float* __restrict__ a6, const float* __restrict__ a7,
             const float* __restrict__ a8, const float* __restrict__ a9,
             bf16_t* __restrict__ dst)
{
    const int off[11] = {0,1179648,2359296,2420736,2482176,2519040,
                         2555904,3145728,3735552,4915200,5505024};
    const float* srcs[10] = {a0,a1,a2,a3,a4,a5,a6,a7,a8,a9};
    int idx = blockIdx.x*256 + threadIdx.x;
    if (idx >= 5505024) return;
    int seg = 0;
    while (idx >= off[seg+1]) ++seg;
    dst[idx] = (bf16_t)srcs[seg][idx - off[seg]];
}

// ---------------- LayerNorm (per token, C=768, 256 thr = 3 elem/thr) --------
__global__ __launch_bounds__(256)
void ln_k(const float* __restrict__ x, const float* __restrict__ g,
          const float* __restrict__ bta, float* __restrict__ xn)
{
    int row = blockIdx.x;
    const float* xr = x + (long)row*CC;
    int tid = threadIdx.x;
    float v[3];
#pragma unroll
    for (int r=0;r<3;++r) v[r] = xr[tid + 256*r];
    float s  = v[0]+v[1]+v[2];
    float s2 = v[0]*v[0]+v[1]*v[1]+v[2]*v[2];
    __shared__ float red[8];
    for (int o=32;o;o>>=1){ s += __shfl_down(s,o); s2 += __shfl_down(s2,o); }
    int wv = tid>>6, ln = tid&63;
    if (ln==0){ red[wv]=s; red[4+wv]=s2; }
    __syncthreads();
    if (tid==0){
        red[0] = red[0]+red[1]+red[2]+red[3];
        red[4] = red[4]+red[5]+red[6]+red[7];
    }
    __syncthreads();
    float mu  = red[0]*(1.0f/CC);
    float var = red[4]*(1.0f/CC) - mu*mu;
    float rstd = rsqrtf(var + 1e-6f);
#pragma unroll
    for (int r=0;r<3;++r){
        int c = tid + 256*r;
        xn[(long)row*CC + c] = (v[r]-mu)*rstd*g[c] + bta[c];
    }
}

// ---------------- depthwise causal conv (k=4) + silu ------------------------
__global__ __launch_bounds__(256)
void conv_k(const float* __restrict__ xz, const float* __restrict__ cw,
            const float* __restrict__ cb, float* __restrict__ xc)
{
    int idx = blockIdx.x*256 + threadIdx.x;
    if (idx >= MTOK*DINNER) return;
    int d = idx % DINNER; int row = idx / DINNER;
    int t = row % LL; int b4 = row - t;
    float acc = cb[d];
#pragma unroll
    for (int k=0;k<4;++k){
        int tt = t - 3 + k;
        if (tt >= 0) acc += cw[d*4 + k] * xz[(long)(b4 + tt)*1536 + d];
    }
    xc[idx] = silu_f(acc);
}

// ---------------- GEMM: C = A(fp32, opt row-gather) @ W(bf16, NxK)^T --------
// GATHER/SCATTER: 0 none, 1 fwd (scan_idx[t]), 2 bwd (scan_idx[L-1-t])
// EPI: 0 store, 1 softplus(bias+v), 3 gelu(bias+v), 4 bias+v+resid
template<int GATHER, int SCATTER, int EPI>
__global__ __launch_bounds__(256)
void gemm_k(const float* __restrict__ A, int lda,
            const bf16_t* __restrict__ W, int N, int K,
            float* __restrict__ Cout, int ldc, int ccol,
            const float* __restrict__ bias,
            const float* __restrict__ resid,
            const int* __restrict__ sidx)
{
    const int lane = threadIdx.x & 63;
    const int wv   = threadIdx.x >> 6;
    const int ln16 = lane & 15;
    const int q    = lane >> 4;

    const int m0 = blockIdx.y*128 + (wv>>1)*64;
    const int n0 = blockIdx.x*128 + (wv&1)*64;

    const float* aptr[4];
#pragma unroll
    for (int i=0;i<4;++i){
        int r = m0 + i*16 + ln16;
        int sr = r;
        if (GATHER != 0){
            int t = r % LL; int bo = r - t;
            sr = bo + ((GATHER==1) ? sidx[t] : sidx[LL-1-t]);
        }
        aptr[i] = A + (long)sr*lda;
    }
    const bf16_t* bptr[4];
    bool bval[4];
#pragma unroll
    for (int j=0;j<4;++j){
        int n = n0 + j*16 + ln16;
        bval[j] = (n < N);
        bptr[j] = W + (long)(bval[j] ? n : 0)*K;
    }

    f32x4 acc[4][4];
#pragma unroll
    for (int i=0;i<4;++i)
#pragma unroll
      for (int j=0;j<4;++j) acc[i][j] = (f32x4){0.f,0.f,0.f,0.f};

    for (int k0 = 0; k0 < K; k0 += 32){
        int kq = k0 + q*8;
        bool kval = (kq < K);
        bf16x8 af[4], bf[4];
#pragma unroll
        for (int i=0;i<4;++i){
            if (kval){
                const float4* p = (const float4*)(aptr[i] + kq);
                float4 v0 = p[0], v1 = p[1];
                bf16x8 t;
                t[0]=(bf16_t)v0.x; t[1]=(bf16_t)v0.y; t[2]=(bf16_t)v0.z; t[3]=(bf16_t)v0.w;
                t[4]=(bf16_t)v1.x; t[5]=(bf16_t)v1.y; t[6]=(bf16_t)v1.z; t[7]=(bf16_t)v1.w;
                af[i] = t;
            } else af[i] = bzero8();
        }
#pragma unroll
        for (int j=0;j<4;++j){
            bf[j] = (kval && bval[j]) ? *(const bf16x8*)(bptr[j] + kq) : bzero8();
        }
#pragma unroll
        for (int i=0;i<4;++i)
#pragma unroll
          for (int j=0;j<4;++j)
            acc[i][j] = __builtin_amdgcn_mfma_f32_16x16x32_bf16(af[i], bf[j], acc[i][j], 0,0,0);
    }

#pragma unroll
    for (int i=0;i<4;++i){
#pragma unroll
        for (int reg=0; reg<4; ++reg){
            int r = m0 + i*16 + q*4 + reg;
            int orow = r;
            if (SCATTER != 0){
                int t = r % LL; int bo = r - t;
                orow = bo + ((SCATTER==1) ? sidx[t] : sidx[LL-1-t]);
            }
#pragma unroll
            for (int j=0;j<4;++j){
                int col = n0 + j*16 + ln16;
                if (col >= N) continue;
                float v = acc[i][j][reg];
                if (EPI==1){ v += bias[col]; v = fmaxf(v,0.f) + log1pf(__expf(-fabsf(v))); }
                else if (EPI==3){ v += bias[col]; v = 0.5f*v*(1.0f + erff(v*0.70710678118654752f)); }
                else if (EPI==4){ v += bias[col] + resid[(long)r*CC + col]; }
                Cout[(long)orow*ldc + ccol + col] = v;
            }
        }
    }
}

// ---------------- chunked selective scan ------------------------------------
// pass1: per-chunk local scan -> Aprod (prod of dA), Hend (local final h)
__global__ __launch_bounds__(256)
void scan1_k(const float* __restrict__ dtp, const float* __restrict__ xcp,
             const float* __restrict__ xdbl, const float* __restrict__ A_log,
             float* __restrict__ Aprod, float* __restrict__ Hend)
{
    int blk = blockIdx.x;
    int dblk = blk % 48; int tmp = blk / 48;
    int j = tmp % NCH; int b = tmp / NCH;
    int s = threadIdx.x & 15;
    int d = dblk*16 + (threadIdx.x >> 4);
    float a_c = -__expf(A_log[d*DSTATE + s]);
    float h = 0.f, ap = 1.f;
    int tbase = b*LL + j*LCH;
    for (int tt=0; tt<LCH; ++tt){
        long row = tbase + tt;
        float dt = dtp[row*DINNER + d];
        float xv = xcp[row*DINNER + d];
        float Bv = xdbl[row*80 + DTRANK + s];
        float da = __expf(dt * a_c);
        h = da*h + dt*xv*Bv;
        ap *= da;
    }
    long o = ((long)(b*NCH + j)*DINNER + d)*DSTATE + s;
    Aprod[o] = ap; Hend[o] = h;
}

// pass2: sequential combine across 16 chunks -> Hin (carry-in per chunk)
__global__ __launch_bounds__(256)
void scan2_k(const float* __restrict__ Aprod, const float* __restrict__ Hend,
             float* __restrict__ Hin)
{
    int idx = blockIdx.x*256 + threadIdx.x;
    if (idx >= BB*DINNER*DSTATE) return;
    int b = idx / (DINNER*DSTATE);
    int ds = idx % (DINNER*DSTATE);
    float h = 0.f;
    for (int j=0;j<NCH;++j){
        long o = (long)(b*NCH+j)*DINNER*DSTATE + ds;
        Hin[o] = h;
        h = Aprod[o]*h + Hend[o];
    }
}

// pass3: re-scan with carry-in, emit y = (scan_y + Dp*xc) * silu(z)
__global__ __launch_bounds__(256)
void scan3_k(const float* __restrict__ dtp, const float* __restrict__ xcp,
             const float* __restrict__ xdbl, const float* __restrict__ xz,
             const float* __restrict__ A_log, const float* __restrict__ Dp,
             const float* __restrict__ Hin, float* __restrict__ yout)
{
    int blk = blockIdx.x;
    int dblk = blk % 48; int tmp = blk / 48;
    int j = tmp % NCH; int b = tmp / NCH;
    int s = threadIdx.x & 15;
    int d = dblk*16 + (threadIdx.x >> 4);
    float a_c = -__expf(A_log[d*DSTATE + s]);
    long o = ((long)(b*NCH + j)*DINNER + d)*DSTATE + s;
    float h = Hin[o];
    float dpv = Dp[d];
    int tbase = b*LL + j*LCH;
    for (int tt=0; tt<LCH; ++tt){
        long row = tbase + tt;
        float dt = dtp[row*DINNER + d];
        float xv = xcp[row*DINNER + d];
        float Bv = xdbl[row*80 + DTRANK + s];
        float Cv = xdbl[row*80 + DTRANK + DSTATE + s];
        float da = __expf(dt * a_c);
        h = da*h + dt*xv*Bv;
        float p = h*Cv;
        p += __shfl_xor(p, 1, 16);
        p += __shfl_xor(p, 2, 16);
        p += __shfl_xor(p, 4, 16);
        p += __shfl_xor(p, 8, 16);
        if (s == 0){
            float y = p + dpv*xv;
            float z = xz[row*1536 + DINNER + d];
            y *= silu_f(z);
            yout[row*DINNER + d] = y;
        }
    }
}

// ----------------------------------------------------------------------------
extern "C" void kernel_launch(void* const* d_in, const int* in_sizes, int n_in,
                              void* d_out, int out_size, void* d_ws, size_t ws_size,
                              hipStream_t stream)
{
    const float* x       = (const float*)d_in[0];
    const int*   sidx    = (const int*)  d_in[1];
    const float* norm_g  = (const float*)d_in[2];
    const float* norm_b  = (const float*)d_in[3];
    const float* fuse_w1 = (const float*)d_in[4];
    const float* fuse_b1 = (const float*)d_in[5];
    const float* fuse_w2 = (const float*)d_in[6];
    const float* fuse_b2 = (const float*)d_in[7];
    // f_: 8..16  b_: 17..25  (in_w, conv_w, conv_b, xproj_w, dt_w, dt_b, A_log, Dp, out_w)
    const float* f_in_w   = (const float*)d_in[8];
    const float* f_conv_w = (const float*)d_in[9];
    const float* f_conv_b = (const float*)d_in[10];
    const float* f_xproj  = (const float*)d_in[11];
    const float* f_dt_w   = (const float*)d_in[12];
    const float* f_dt_b   = (const float*)d_in[13];
    const float* f_A_log  = (const float*)d_in[14];
    const float* f_Dp     = (const float*)d_in[15];
    const float* f_out_w  = (const float*)d_in[16];
    const float* b_in_w   = (const float*)d_in[17];
    const float* b_conv_w = (const float*)d_in[18];
    const float* b_conv_b = (const float*)d_in[19];
    const float* b_xproj  = (const float*)d_in[20];
    const float* b_dt_w   = (const float*)d_in[21];
    const float* b_dt_b   = (const float*)d_in[22];
    const float* b_A_log  = (const float*)d_in[23];
    const float* b_Dp     = (const float*)d_in[24];
    const float* b_out_w  = (const float*)d_in[25];
    float* out = (float*)d_out;

    // ---- workspace layout (floats) ----
    float* ws    = (float*)d_ws;
    float* xn    = ws;                    // 7,077,888
    float* xz    = xn    + 7077888;       // 14,155,776 (per-direction, reused)
    float* xc    = xz    + 14155776;      // 7,077,888
    float* xdbl  = xc    + 7077888;       // 737,280
    float* dtb   = xdbl  + 737280;        // 7,077,888
    float* yb    = dtb   + 7077888;       // 7,077,888 (also reused as h1)
    float* fused = yb    + 7077888;       // 14,155,776
    float* Aprod = fused + 14155776;      // 786,432
    float* Hend  = Aprod + 786432;        // 786,432
    float* Hin   = Hend  + 786432;        // 786,432
    bf16_t* wbf  = (bf16_t*)(Hin + 786432); // 5,505,024 bf16
    float* h1 = yb;

    bf16_t* w_fin = wbf + 0;
    bf16_t* w_bin = wbf + 1179648;
    bf16_t* w_fxp = wbf + 2359296;
    bf16_t* w_bxp = wbf + 2420736;
    bf16_t* w_fdt = wbf + 2482176;
    bf16_t* w_bdt = wbf + 2519040;
    bf16_t* w_fout= wbf + 2555904;
    bf16_t* w_bout= wbf + 3145728;
    bf16_t* w_1   = wbf + 3735552;
    bf16_t* w_2   = wbf + 4915200;

    // weights -> bf16
    wconv_k<<<21504, 256, 0, stream>>>(f_in_w, b_in_w, f_xproj, b_xproj,
                                       f_dt_w, b_dt_w, f_out_w, b_out_w,
                                       fuse_w1, fuse_w2, wbf);
    // layernorm (original token order)
    ln_k<<<MTOK, 256, 0, stream>>>(x, norm_g, norm_b, xn);

    dim3 g_in(12, 72), g_xd(1, 72), g_768(6, 72);

    // ================= forward direction =================
    gemm_k<1,0,0><<<g_in, 256, 0, stream>>>(xn, CC, w_fin, 1536, 768,
                                            xz, 1536, 0, nullptr, nullptr, sidx);
    conv_k<<<27648, 256, 0, stream>>>(xz, f_conv_w, f_conv_b, xc);
    gemm_k<0,0,0><<<g_xd, 256, 0, stream>>>(xc, DINNER, w_fxp, 80, 768,
                                            xdbl, 80, 0, nullptr, nullptr, nullptr);
    gemm_k<0,0,1><<<g_768, 256, 0, stream>>>(xdbl, 80, w_fdt, 768, 48,
                                             dtb, 768, 0, f_dt_b, nullptr, nullptr);
    scan1_k<<<3072, 256, 0, stream>>>(dtb, xc, xdbl, f_A_log, Aprod, Hend);
    scan2_k<<<192, 256, 0, stream>>>(Aprod, Hend, Hin);
    scan3_k<<<3072, 256, 0, stream>>>(dtb, xc, xdbl, xz, f_A_log, f_Dp, Hin, yb);
    gemm_k<0,1,0><<<g_768, 256, 0, stream>>>(yb, DINNER, w_fout, 768, 768,
                                             fused, 1536, 0, nullptr, nullptr, sidx);

    // ================= backward direction =================
    gemm_k<2,0,0><<<g_in, 256, 0, stream>>>(xn, CC, w_bin, 1536, 768,
                                            xz, 1536, 0, nullptr, nullptr, sidx);
    conv_k<<<27648, 256, 0, stream>>>(xz, b_conv_w, b_conv_b, xc);
    gemm_k<0,0,0><<<g_xd, 256, 0, stream>>>(xc, DINNER, w_bxp, 80, 768,
                                            xdbl, 80, 0, nullptr, nullptr, nullptr);
    gemm_k<0,0,1><<<g_768, 256, 0, stream>>>(xdbl, 80, w_bdt, 768, 48,
                                             dtb, 768, 0, b_dt_b, nullptr, nullptr);
    scan1_k<<<3072, 256, 0, stream>>>(dtb, xc, xdbl, b_A_log, Aprod, Hend);
    scan2_k<<<192, 256, 0, stream>>>(Aprod, Hend, Hin);
    scan3_k<<<3072, 256, 0, stream>>>(dtb, xc, xdbl, xz, b_A_log, b_Dp, Hin, yb);
    gemm_k<0,2,0><<<g_768, 256, 0, stream>>>(yb, DINNER, w_bout, 768, 768,
                                             fused, 1536, 768, nullptr, nullptr, sidx);

    // ================= fusion MLP + residual =================
    gemm_k<0,0,3><<<g_768, 256, 0, stream>>>(fused, 1536, w_1, 768, 1536,
                                             h1, 768, 0, fuse_b1, nullptr, nullptr);
    gemm_k<0,0,4><<<g_768, 256, 0, stream>>>(h1, DINNER, w_2, 768, 768,
                                             out, 768, 0, fuse_b2, x, nullptr);
}

// Round 2
// 1278.920 us; speedup vs baseline: 1.2509x; 1.2509x over previous
//
#include <hip/hip_runtime.h>
#include <hip/hip_bf16.h>
#include <cmath>

#define BB 4
#define LL 2304
#define CC 768
#define DSTATE 16
#define DINNER 768
#define DTRANK 48
#define MTOK (BB*LL)          // 9216
#define NCH 24
#define LCH (LL/NCH)          // 96

typedef __bf16 bf16_t;
typedef __bf16 bf16x8 __attribute__((ext_vector_type(8)));
typedef float  f32x4  __attribute__((ext_vector_type(4)));

__device__ __forceinline__ float silu_f(float v){ return v / (1.0f + __expf(-v)); }

__device__ __forceinline__ bf16x8 bzero8(){
    bf16x8 v;
#pragma unroll
    for (int i=0;i<8;++i) v[i] = (bf16_t)0.0f;
    return v;
}

// ---------------- weight fp32 -> bf16 conversion (all 10 weight matrices) ----
__global__ __launch_bounds__(256)
void wconv_k(const float* __restrict__ a0, const float* __restrict__ a1,
             const float* __restrict__ a2, const float* __restrict__ a3,
             const float* __restrict__ a4, const float* __restrict__ a5,
             const float* __restrict__ a6, const float* __restrict__ a7,
             const float* __restrict__ a8, const float* __restrict__ a9,
             bf16_t* __restrict__ dst)
{
    const int off[11] = {0,1179648,2359296,2420736,2482176,2519040,
                         2555904,3145728,3735552,4915200,5505024};
    const float* srcs[10] = {a0,a1,a2,a3,a4,a5,a6,a7,a8,a9};
    int idx = blockIdx.x*256 + threadIdx.x;
    if (idx >= 5505024) return;
    int seg = 0;
    while (idx >= off[seg+1]) ++seg;
    dst[idx] = (bf16_t)srcs[seg][idx - off[seg]];
}

// ---------------- LayerNorm (per token, C=768, 256 thr = 3 elem/thr) --------
__global__ __launch_bounds__(256)
void ln_k(const float* __restrict__ x, const float* __restrict__ g,
          const float* __restrict__ bta, float* __restrict__ xn)
{
    int row = blockIdx.x;
    const float* xr = x + (long)row*CC;
    int tid = threadIdx.x;
    float v[3];
#pragma unroll
    for (int r=0;r<3;++r) v[r] = xr[tid + 256*r];
    float s  = v[0]+v[1]+v[2];
    float s2 = v[0]*v[0]+v[1]*v[1]+v[2]*v[2];
    __shared__ float red[8];
    for (int o=32;o;o>>=1){ s += __shfl_down(s,o); s2 += __shfl_down(s2,o); }
    int wv = tid>>6, ln = tid&63;
    if (ln==0){ red[wv]=s; red[4+wv]=s2; }
    __syncthreads();
    if (tid==0){
        red[0] = red[0]+red[1]+red[2]+red[3];
        red[4] = red[4]+red[5]+red[6]+red[7];
    }
    __syncthreads();
    float mu  = red[0]*(1.0f/CC);
    float var = red[4]*(1.0f/CC) - mu*mu;
    float rstd = rsqrtf(var + 1e-6f);
#pragma unroll
    for (int r=0;r<3;++r){
        int c = tid + 256*r;
        xn[(long)row*CC + c] = (v[r]-mu)*rstd*g[c] + bta[c];
    }
}

// ---------------- depthwise causal conv (k=4) + silu ------------------------
__global__ __launch_bounds__(256)
void conv_k(const float* __restrict__ xz, const float* __restrict__ cw,
            const float* __restrict__ cb, float* __restrict__ xc)
{
    int idx = blockIdx.x*256 + threadIdx.x;
    if (idx >= MTOK*DINNER) return;
    int d = idx % DINNER; int row = idx / DINNER;
    int t = row % LL; int b4 = row - t;
    float acc = cb[d];
#pragma unroll
    for (int k=0;k<4;++k){
        int tt = t - 3 + k;
        if (tt >= 0) acc += cw[d*4 + k] * xz[(long)(b4 + tt)*1536 + d];
    }
    xc[idx] = silu_f(acc);
}

// ---------------- GEMM: C = A(fp32, opt row-gather) @ W(bf16, NxK)^T --------
// GATHER/SCATTER: 0 none, 1 fwd (scan_idx[t]), 2 bwd (scan_idx[L-1-t])
// EPI: 0 store, 1 softplus(bias+v), 3 gelu(bias+v), 4 bias+v+resid
template<int GATHER, int SCATTER, int EPI>
__global__ __launch_bounds__(256)
void gemm_k(const float* __restrict__ A, int lda,
            const bf16_t* __restrict__ W, int N, int K,
            float* __restrict__ Cout, int ldc, int ccol,
            const float* __restrict__ bias,
            const float* __restrict__ resid,
            const int* __restrict__ sidx)
{
    const int lane = threadIdx.x & 63;
    const int wv   = threadIdx.x >> 6;
    const int ln16 = lane & 15;
    const int q    = lane >> 4;

    const int m0 = blockIdx.y*128 + (wv>>1)*64;
    const int n0 = blockIdx.x*128 + (wv&1)*64;

    const float* aptr[4];
#pragma unroll
    for (int i=0;i<4;++i){
        int r = m0 + i*16 + ln16;
        int sr = r;
        if (GATHER != 0){
            int t = r % LL; int bo = r - t;
            sr = bo + ((GATHER==1) ? sidx[t] : sidx[LL-1-t]);
        }
        aptr[i] = A + (long)sr*lda;
    }
    const bf16_t* bptr[4];
    bool bval[4];
#pragma unroll
    for (int j=0;j<4;++j){
        int n = n0 + j*16 + ln16;
        bval[j] = (n < N);
        bptr[j] = W + (long)(bval[j] ? n : 0)*K;
    }

    f32x4 acc[4][4];
#pragma unroll
    for (int i=0;i<4;++i)
#pragma unroll
      for (int j=0;j<4;++j) acc[i][j] = (f32x4){0.f,0.f,0.f,0.f};

    for (int k0 = 0; k0 < K; k0 += 32){
        int kq = k0 + q*8;
        bool kval = (kq < K);
        bf16x8 af[4], bf[4];
#pragma unroll
        for (int i=0;i<4;++i){
            if (kval){
                const float4* p = (const float4*)(aptr[i] + kq);
                float4 v0 = p[0], v1 = p[1];
                bf16x8 t;
                t[0]=(bf16_t)v0.x; t[1]=(bf16_t)v0.y; t[2]=(bf16_t)v0.z; t[3]=(bf16_t)v0.w;
                t[4]=(bf16_t)v1.x; t[5]=(bf16_t)v1.y; t[6]=(bf16_t)v1.z; t[7]=(bf16_t)v1.w;
                af[i] = t;
            } else af[i] = bzero8();
        }
#pragma unroll
        for (int j=0;j<4;++j){
            bf[j] = (kval && bval[j]) ? *(const bf16x8*)(bptr[j] + kq) : bzero8();
        }
#pragma unroll
        for (int i=0;i<4;++i)
#pragma unroll
          for (int j=0;j<4;++j)
            acc[i][j] = __builtin_amdgcn_mfma_f32_16x16x32_bf16(af[i], bf[j], acc[i][j], 0,0,0);
    }

#pragma unroll
    for (int i=0;i<4;++i){
#pragma unroll
        for (int reg=0; reg<4; ++reg){
            int r = m0 + i*16 + q*4 + reg;
            int orow = r;
            if (SCATTER != 0){
                int t = r % LL; int bo = r - t;
                orow = bo + ((SCATTER==1) ? sidx[t] : sidx[LL-1-t]);
            }
#pragma unroll
            for (int j=0;j<4;++j){
                int col = n0 + j*16 + ln16;
                if (col >= N) continue;
                float v = acc[i][j][reg];
                if (EPI==1){ v += bias[col]; v = fmaxf(v,0.f) + log1pf(__expf(-fabsf(v))); }
                else if (EPI==3){ v += bias[col]; v = 0.5f*v*(1.0f + erff(v*0.70710678118654752f)); }
                else if (EPI==4){ v += bias[col] + resid[(long)r*CC + col]; }
                Cout[(long)orow*ldc + ccol + col] = v;
            }
        }
    }
}

// ---------------- chunked selective scan (restructured) ---------------------
// Thread layout (per block of 256 = 4 waves):
//   lane = tid&63; d_low = lane&15; sg = lane>>4 (4 s-states per thread)
//   wave w covers d = dblk*64 + w*16 + d_low; thread owns s = sg*4 .. sg*4+3
// Grid: BB * NCH * 12 blocks (12 dblks of 64 d).
// pass1: local scan -> Aprod = exp(a * sum_dt), Hend = local final h
__global__ __launch_bounds__(256)
void scan1_k(const float* __restrict__ dtp, const float* __restrict__ xcp,
             const float* __restrict__ xdbl, const float* __restrict__ A_log,
             float* __restrict__ Aprod, float* __restrict__ Hend)
{
    int blk = blockIdx.x;
    int dblk = blk % 12; int tmp = blk / 12;
    int j = tmp % NCH; int b = tmp / NCH;
    int lane = threadIdx.x & 63;
    int wave = threadIdx.x >> 6;
    int d_low = lane & 15;
    int sg = lane >> 4;
    int d = dblk*64 + wave*16 + d_low;

    f32x4 al = *(const f32x4*)&A_log[d*DSTATE + sg*4];
    float a_c[4];
#pragma unroll
    for (int k=0;k<4;++k) a_c[k] = -__expf(al[k]);

    long tbase = (long)b*LL + (long)j*LCH;
    const float* pd = dtp  + tbase*DINNER + d;
    const float* px = xcp  + tbase*DINNER + d;
    const float* pB = xdbl + tbase*80 + DTRANK + sg*4;

    float h[4] = {0.f,0.f,0.f,0.f};
    float sdt = 0.f;
    for (int tt=0; tt<LCH; ++tt){
        float dt = *pd; pd += DINNER;
        float xv = *px; px += DINNER;
        f32x4 Bv = *(const f32x4*)pB; pB += 80;
        float c = dt*xv;
        sdt += dt;
#pragma unroll
        for (int k=0;k<4;++k){
            float da = __expf(dt * a_c[k]);
            h[k] = da*h[k] + c*Bv[k];
        }
    }
    long o = ((long)(b*NCH + j)*DINNER + d)*DSTATE + sg*4;
    f32x4 ap, hv;
#pragma unroll
    for (int k=0;k<4;++k){ ap[k] = __expf(sdt * a_c[k]); hv[k] = h[k]; }
    *(f32x4*)&Aprod[o] = ap;
    *(f32x4*)&Hend[o]  = hv;
}

// pass2: sequential combine across NCH chunks; writes carry-in IN PLACE into
// Aprod (Aprod[chunk j] becomes h_in for chunk j).
__global__ __launch_bounds__(256)
void scan2_k(float* __restrict__ Aprod, const float* __restrict__ Hend)
{
    int idx = blockIdx.x*256 + threadIdx.x;
    if (idx >= BB*DINNER*DSTATE) return;
    int b = idx / (DINNER*DSTATE);
    int ds = idx % (DINNER*DSTATE);
    float h = 0.f;
    for (int j=0;j<NCH;++j){
        long o = (long)(b*NCH+j)*DINNER*DSTATE + ds;
        float ap = Aprod[o];
        float he = Hend[o];
        Aprod[o] = h;          // carry-in for this chunk
        h = ap*h + he;
    }
}

// pass3: re-scan with carry-in (from Aprod), emit y = (scan_y + Dp*xc)*silu(z)
__global__ __launch_bounds__(256)
void scan3_k(const float* __restrict__ dtp, const float* __restrict__ xcp,
             const float* __restrict__ xdbl, const float* __restrict__ xz,
             const float* __restrict__ A_log, const float* __restrict__ Dp,
             const float* __restrict__ Hin, float* __restrict__ yout)
{
    int blk = blockIdx.x;
    int dblk = blk % 12; int tmp = blk / 12;
    int j = tmp % NCH; int b = tmp / NCH;
    int lane = threadIdx.x & 63;
    int wave = threadIdx.x >> 6;
    int d_low = lane & 15;
    int sg = lane >> 4;
    int d = dblk*64 + wave*16 + d_low;

    f32x4 al = *(const f32x4*)&A_log[d*DSTATE + sg*4];
    float a_c[4];
#pragma unroll
    for (int k=0;k<4;++k) a_c[k] = -__expf(al[k]);
    float dpv = Dp[d];

    long o = ((long)(b*NCH + j)*DINNER + d)*DSTATE + sg*4;
    f32x4 hin = *(const f32x4*)&Hin[o];
    float h[4];
#pragma unroll
    for (int k=0;k<4;++k) h[k] = hin[k];

    long tbase = (long)b*LL + (long)j*LCH;
    const float* pd = dtp  + tbase*DINNER + d;
    const float* px = xcp  + tbase*DINNER + d;
    const float* pB = xdbl + tbase*80 + DTRANK + sg*4;
    const float* pC = xdbl + tbase*80 + DTRANK + DSTATE + sg*4;
    const float* pz = xz   + tbase*1536 + DINNER + d;
    float*       py = yout + tbase*DINNER + d;

    for (int tt=0; tt<LCH; ++tt){
        float dt = *pd; pd += DINNER;
        float xv = *px; px += DINNER;
        f32x4 Bv = *(const f32x4*)pB; pB += 80;
        f32x4 Cv = *(const f32x4*)pC; pC += 80;
        float z  = *pz; pz += 1536;
        float c = dt*xv;
        float p = 0.f;
#pragma unroll
        for (int k=0;k<4;++k){
            float da = __expf(dt * a_c[k]);
            h[k] = da*h[k] + c*Bv[k];
            p += h[k]*Cv[k];
        }
        p += __shfl_xor(p, 16);
        p += __shfl_xor(p, 32);
        if (sg == 0){
            float y = (p + dpv*xv) * silu_f(z);
            *py = y;
        }
        py += DINNER;
    }
}

// ----------------------------------------------------------------------------
extern "C" void kernel_launch(void* const* d_in, const int* in_sizes, int n_in,
                              void* d_out, int out_size, void* d_ws, size_t ws_size,
                              hipStream_t stream)
{
    const float* x       = (const float*)d_in[0];
    const int*   sidx    = (const int*)  d_in[1];
    const float* norm_g  = (const float*)d_in[2];
    const float* norm_b  = (const float*)d_in[3];
    const float* fuse_w1 = (const float*)d_in[4];
    const float* fuse_b1 = (const float*)d_in[5];
    const float* fuse_w2 = (const float*)d_in[6];
    const float* fuse_b2 = (const float*)d_in[7];
    const float* f_in_w   = (const float*)d_in[8];
    const float* f_conv_w = (const float*)d_in[9];
    const float* f_conv_b = (const float*)d_in[10];
    const float* f_xproj  = (const float*)d_in[11];
    const float* f_dt_w   = (const float*)d_in[12];
    const float* f_dt_b   = (const float*)d_in[13];
    const float* f_A_log  = (const float*)d_in[14];
    const float* f_Dp     = (const float*)d_in[15];
    const float* f_out_w  = (const float*)d_in[16];
    const float* b_in_w   = (const float*)d_in[17];
    const float* b_conv_w = (const float*)d_in[18];
    const float* b_conv_b = (const float*)d_in[19];
    const float* b_xproj  = (const float*)d_in[20];
    const float* b_dt_w   = (const float*)d_in[21];
    const float* b_dt_b   = (const float*)d_in[22];
    const float* b_A_log  = (const float*)d_in[23];
    const float* b_Dp     = (const float*)d_in[24];
    const float* b_out_w  = (const float*)d_in[25];
    float* out = (float*)d_out;

    // ---- workspace layout (floats) — total 62,472,192 fl = 249.9 MB ----
    float* ws    = (float*)d_ws;
    float* xn    = ws;                    // 7,077,888
    float* xz    = xn    + 7077888;       // 14,155,776 (per-direction, reused)
    float* xc    = xz    + 14155776;      // 7,077,888
    float* xdbl  = xc    + 7077888;       // 737,280
    float* dtb   = xdbl  + 737280;        // 7,077,888
    float* yb    = dtb   + 7077888;       // 7,077,888 (also reused as h1)
    float* fused = yb    + 7077888;       // 14,155,776
    float* Aprod = fused + 14155776;      // 1,179,648 (NCH=24)
    float* Hend  = Aprod + 1179648;       // 1,179,648
    bf16_t* wbf  = (bf16_t*)(Hend + 1179648); // 5,505,024 bf16 = 2,752,512 fl
    float* h1 = yb;

    bf16_t* w_fin = wbf + 0;
    bf16_t* w_bin = wbf + 1179648;
    bf16_t* w_fxp = wbf + 2359296;
    bf16_t* w_bxp = wbf + 2420736;
    bf16_t* w_fdt = wbf + 2482176;
    bf16_t* w_bdt = wbf + 2519040;
    bf16_t* w_fout= wbf + 2555904;
    bf16_t* w_bout= wbf + 3145728;
    bf16_t* w_1   = wbf + 3735552;
    bf16_t* w_2   = wbf + 4915200;

    // weights -> bf16
    wconv_k<<<21504, 256, 0, stream>>>(f_in_w, b_in_w, f_xproj, b_xproj,
                                       f_dt_w, b_dt_w, f_out_w, b_out_w,
                                       fuse_w1, fuse_w2, wbf);
    // layernorm (original token order)
    ln_k<<<MTOK, 256, 0, stream>>>(x, norm_g, norm_b, xn);

    dim3 g_in(12, 72), g_xd(1, 72), g_768(6, 72);
    const int scan_blocks = BB*NCH*12;   // 1152

    // ================= forward direction =================
    gemm_k<1,0,0><<<g_in, 256, 0, stream>>>(xn, CC, w_fin, 1536, 768,
                                            xz, 1536, 0, nullptr, nullptr, sidx);
    conv_k<<<27648, 256, 0, stream>>>(xz, f_conv_w, f_conv_b, xc);
    gemm_k<0,0,0><<<g_xd, 256, 0, stream>>>(xc, DINNER, w_fxp, 80, 768,
                                            xdbl, 80, 0, nullptr, nullptr, nullptr);
    gemm_k<0,0,1><<<g_768, 256, 0, stream>>>(xdbl, 80, w_fdt, 768, 48,
                                             dtb, 768, 0, f_dt_b, nullptr, nullptr);
    scan1_k<<<scan_blocks, 256, 0, stream>>>(dtb, xc, xdbl, f_A_log, Aprod, Hend);
    scan2_k<<<192, 256, 0, stream>>>(Aprod, Hend);
    scan3_k<<<scan_blocks, 256, 0, stream>>>(dtb, xc, xdbl, xz, f_A_log, f_Dp, Aprod, yb);
    gemm_k<0,1,0><<<g_768, 256, 0, stream>>>(yb, DINNER, w_fout, 768, 768,
                                             fused, 1536, 0, nullptr, nullptr, sidx);

    // ================= backward direction =================
    gemm_k<2,0,0><<<g_in, 256, 0, stream>>>(xn, CC, w_bin, 1536, 768,
                                            xz, 1536, 0, nullptr, nullptr, sidx);
    conv_k<<<27648, 256, 0, stream>>>(xz, b_conv_w, b_conv_b, xc);
    gemm_k<0,0,0><<<g_xd, 256, 0, stream>>>(xc, DINNER, w_bxp, 80, 768,
                                            xdbl, 80, 0, nullptr, nullptr, nullptr);
    gemm_k<0,0,1><<<g_768, 256, 0, stream>>>(xdbl, 80, w_bdt, 768, 48,
                                             dtb, 768, 0, b_dt_b, nullptr, nullptr);
    scan1_k<<<scan_blocks, 256, 0, stream>>>(dtb, xc, xdbl, b_A_log, Aprod, Hend);
    scan2_k<<<192, 256, 0, stream>>>(Aprod, Hend);
    scan3_k<<<scan_blocks, 256, 0, stream>>>(dtb, xc, xdbl, xz, b_A_log, b_Dp, Aprod, yb);
    gemm_k<0,2,0><<<g_768, 256, 0, stream>>>(yb, DINNER, w_bout, 768, 768,
                                             fused, 1536, 768, nullptr, nullptr, sidx);

    // ================= fusion MLP + residual =================
    gemm_k<0,0,3><<<g_768, 256, 0, stream>>>(fused, 1536, w_1, 768, 1536,
                                             h1, 768, 0, fuse_b1, nullptr, nullptr);
    gemm_k<0,0,4><<<g_768, 256, 0, stream>>>(h1, DINNER, w_2, 768, 768,
                                             out, 768, 0, fuse_b2, x, nullptr);
}

// Round 3
// 1208.822 us; speedup vs baseline: 1.3234x; 1.0580x over previous
//
#include <hip/hip_runtime.h>
#include <hip/hip_bf16.h>
#include <cmath>

#define BB 4
#define LL 2304
#define CC 768
#define DSTATE 16
#define DINNER 768
#define DTRANK 48
#define MTOK (BB*LL)          // 9216
#define NCH 24
#define LCH (LL/NCH)          // 96

typedef __bf16 bf16_t;
typedef __bf16 bf16x8 __attribute__((ext_vector_type(8)));
typedef float  f32x4  __attribute__((ext_vector_type(4)));

__device__ __forceinline__ float silu_f(float v){ return v / (1.0f + __expf(-v)); }

__device__ __forceinline__ bf16x8 bzero8(){
    bf16x8 v;
#pragma unroll
    for (int i=0;i<8;++i) v[i] = (bf16_t)0.0f;
    return v;
}

// ---------------- weight fp32 -> bf16 conversion ----------------------------
// segments: f_in, b_in, f_out, b_out, w1, w2, f_bc(xproj rows 48..79), b_bc
__global__ __launch_bounds__(256)
void wconv_k(const float* __restrict__ a0, const float* __restrict__ a1,
             const float* __restrict__ a2, const float* __restrict__ a3,
             const float* __restrict__ a4, const float* __restrict__ a5,
             const float* __restrict__ a6, const float* __restrict__ a7,
             bf16_t* __restrict__ dst)
{
    const int cum[9]  = {0,1179648,2359296,2949120,3538944,4718592,5308416,5332992,5357568};
    const int dofs[8] = {0,1179648,2359296,2949120,3538944,4718592,5898240,6512640};
    const float* srcs[8] = {a0,a1,a2,a3,a4,a5,a6,a7};
    int idx = blockIdx.x*256 + threadIdx.x;
    if (idx >= 5357568) return;
    int seg = 0;
    while (idx >= cum[seg+1]) ++seg;
    dst[dofs[seg] + idx - cum[seg]] = (bf16_t)srcs[seg][idx - cum[seg]];
}

// ---------------- combo weight: dst[n*768+k] = sum_r dtw[n*48+r]*xproj[r*768+k]
__global__ __launch_bounds__(256)
void combo_k(const float* __restrict__ dtw, const float* __restrict__ xproj,
             bf16_t* __restrict__ dst)
{
    __shared__ float row[48];
    int n = blockIdx.x;
    if (threadIdx.x < 48) row[threadIdx.x] = dtw[n*48 + threadIdx.x];
    __syncthreads();
#pragma unroll
    for (int kk=0; kk<3; ++kk){
        int k = threadIdx.x + 256*kk;
        float s = 0.f;
#pragma unroll 8
        for (int r=0; r<48; ++r) s += row[r]*xproj[r*768 + k];
        dst[n*768 + k] = (bf16_t)s;
    }
}

// ---------------- LayerNorm (per token, C=768) -> bf16 ----------------------
__global__ __launch_bounds__(256)
void ln_k(const float* __restrict__ x, const float* __restrict__ g,
          const float* __restrict__ bta, bf16_t* __restrict__ xn)
{
    int row = blockIdx.x;
    const float* xr = x + (long)row*CC;
    int tid = threadIdx.x;
    float v[3];
#pragma unroll
    for (int r=0;r<3;++r) v[r] = xr[tid + 256*r];
    float s  = v[0]+v[1]+v[2];
    float s2 = v[0]*v[0]+v[1]*v[1]+v[2]*v[2];
    __shared__ float red[8];
    for (int o=32;o;o>>=1){ s += __shfl_down(s,o); s2 += __shfl_down(s2,o); }
    int wv = tid>>6, ln = tid&63;
    if (ln==0){ red[wv]=s; red[4+wv]=s2; }
    __syncthreads();
    if (tid==0){
        red[0] = red[0]+red[1]+red[2]+red[3];
        red[4] = red[4]+red[5]+red[6]+red[7];
    }
    __syncthreads();
    float mu  = red[0]*(1.0f/CC);
    float var = red[4]*(1.0f/CC) - mu*mu;
    float rstd = rsqrtf(var + 1e-6f);
#pragma unroll
    for (int r=0;r<3;++r){
        int c = tid + 256*r;
        xn[(long)row*CC + c] = (bf16_t)((v[r]-mu)*rstd*g[c] + bta[c]);
    }
}

// ---------------- depthwise causal conv (k=4) + silu -> bf16 ----------------
__global__ __launch_bounds__(256)
void conv_k(const float* __restrict__ xz, const float* __restrict__ cw,
            const float* __restrict__ cb, bf16_t* __restrict__ xc)
{
    int idx = blockIdx.x*256 + threadIdx.x;
    if (idx >= MTOK*DINNER) return;
    int d = idx % DINNER; int row = idx / DINNER;
    int t = row % LL; int b4 = row - t;
    float acc = cb[d];
#pragma unroll
    for (int k=0;k<4;++k){
        int tt = t - 3 + k;
        if (tt >= 0) acc += cw[d*4 + k] * xz[(long)(b4 + tt)*1536 + d];
    }
    xc[idx] = (bf16_t)silu_f(acc);
}

// ---------------- GEMM2: C = A(bf16, opt row-gather) @ W(bf16, NxK)^T -------
// GATHER/SCATTER: 0 none, 1 fwd (sidx[t]), 2 bwd (sidx[L-1-t])
// EPI: 2 store bf16 | 3 gelu+bias->bf16 | 4 bias+resid->f32 |
//      5 combo split (softplus dt->f32 out1, B/C->f32 out2) | 6 store f32
// Wave layout: 2x2 waves; wave tile = (MI*16) x (NJ*16); block = 2MI*16 x 2NJ*16
template<int GATHER, int SCATTER, int EPI, int MI, int NJ>
__global__ __launch_bounds__(256)
void gemm2_k(const bf16_t* __restrict__ A, int lda,
             const bf16_t* __restrict__ W, int N, int K,
             void* __restrict__ out1, void* __restrict__ out2,
             int ldc, int ccol,
             const float* __restrict__ bias,
             const float* __restrict__ resid,
             const int* __restrict__ sidx)
{
    const int lane = threadIdx.x & 63;
    const int wv   = threadIdx.x >> 6;
    const int ln16 = lane & 15;
    const int q    = lane >> 4;

    const int m0 = blockIdx.y*(2*MI*16) + (wv>>1)*(MI*16);
    const int n0 = blockIdx.x*(2*NJ*16) + (wv&1)*(NJ*16);

    const bf16_t* ap[MI];
#pragma unroll
    for (int i=0;i<MI;++i){
        int r = m0 + i*16 + ln16;
        int sr = r;
        if (GATHER != 0){
            int t = r % LL; int bo = r - t;
            sr = bo + ((GATHER==1) ? sidx[t] : sidx[LL-1-t]);
        }
        ap[i] = A + (long)sr*lda;
    }
    const bf16_t* bp[NJ];
    bool bval[NJ];
#pragma unroll
    for (int j=0;j<NJ;++j){
        int n = n0 + j*16 + ln16;
        bval[j] = (n < N);
        bp[j] = W + (long)(bval[j] ? n : 0)*K;
    }

    f32x4 acc[MI][NJ];
#pragma unroll
    for (int i=0;i<MI;++i)
#pragma unroll
      for (int j=0;j<NJ;++j) acc[i][j] = (f32x4){0.f,0.f,0.f,0.f};

    bf16x8 a0[MI], b0[NJ], a1[MI], b1[NJ];
    const int q8 = q*8;

    // preload k=0
#pragma unroll
    for (int i=0;i<MI;++i) a0[i] = *(const bf16x8*)(ap[i] + q8);
#pragma unroll
    for (int j=0;j<NJ;++j) b0[j] = bval[j] ? *(const bf16x8*)(bp[j] + q8) : bzero8();

    // K is a multiple of 64 for all call sites (768 / 1536)
    for (int k0 = 0; k0 < K; k0 += 64){
        // load k0+32 into buf1
#pragma unroll
        for (int i=0;i<MI;++i) a1[i] = *(const bf16x8*)(ap[i] + k0 + 32 + q8);
#pragma unroll
        for (int j=0;j<NJ;++j) b1[j] = bval[j] ? *(const bf16x8*)(bp[j] + k0 + 32 + q8) : bzero8();
        // MFMA on buf0 (k0)
#pragma unroll
        for (int i=0;i<MI;++i)
#pragma unroll
          for (int j=0;j<NJ;++j)
            acc[i][j] = __builtin_amdgcn_mfma_f32_16x16x32_bf16(a0[i], b0[j], acc[i][j], 0,0,0);
        // load k0+64 into buf0 (if any)
        if (k0 + 64 < K){
#pragma unroll
            for (int i=0;i<MI;++i) a0[i] = *(const bf16x8*)(ap[i] + k0 + 64 + q8);
#pragma unroll
            for (int j=0;j<NJ;++j) b0[j] = bval[j] ? *(const bf16x8*)(bp[j] + k0 + 64 + q8) : bzero8();
        }
        // MFMA on buf1 (k0+32)
#pragma unroll
        for (int i=0;i<MI;++i)
#pragma unroll
          for (int j=0;j<NJ;++j)
            acc[i][j] = __builtin_amdgcn_mfma_f32_16x16x32_bf16(a1[i], b1[j], acc[i][j], 0,0,0);
    }

#pragma unroll
    for (int i=0;i<MI;++i){
#pragma unroll
        for (int reg=0; reg<4; ++reg){
            int r = m0 + i*16 + q*4 + reg;
            int orow = r;
            if (SCATTER != 0){
                int t = r % LL; int bo = r - t;
                orow = bo + ((SCATTER==1) ? sidx[t] : sidx[LL-1-t]);
            }
#pragma unroll
            for (int j=0;j<NJ;++j){
                int col = n0 + j*16 + ln16;
                if (col >= N) continue;
                float v = acc[i][j][reg];
                if (EPI==2){
                    ((bf16_t*)out1)[(long)orow*ldc + ccol + col] = (bf16_t)v;
                } else if (EPI==3){
                    v += bias[col];
                    v = 0.5f*v*(1.0f + erff(v*0.70710678118654752f));
                    ((bf16_t*)out1)[(long)orow*ldc + col] = (bf16_t)v;
                } else if (EPI==4){
                    v += bias[col] + resid[(long)r*CC + col];
                    ((float*)out1)[(long)orow*ldc + col] = v;
                } else if (EPI==5){
                    if (col < 768){
                        v += bias[col];
                        v = fmaxf(v,0.f) + log1pf(__expf(-fabsf(v)));
                        ((float*)out1)[(long)r*768 + col] = v;
                    } else {
                        ((float*)out2)[(long)r*32 + (col-768)] = v;
                    }
                } else { // EPI==6
                    ((float*)out1)[(long)orow*ldc + ccol + col] = v;
                }
            }
        }
    }
}

// ---------------- chunked selective scan ------------------------------------
// pass1: local scan -> Aprod = exp(a*sum_dt), Hend = local final h
__global__ __launch_bounds__(256)
void scan1_k(const float* __restrict__ dtp, const bf16_t* __restrict__ xcp,
             const float* __restrict__ bc, const float* __restrict__ A_log,
             float* __restrict__ Aprod, float* __restrict__ Hend)
{
    int blk = blockIdx.x;
    int dblk = blk % 12; int tmp = blk / 12;
    int j = tmp % NCH; int b = tmp / NCH;
    int lane = threadIdx.x & 63;
    int wave = threadIdx.x >> 6;
    int d_low = lane & 15;
    int sg = lane >> 4;
    int d = dblk*64 + wave*16 + d_low;

    f32x4 al = *(const f32x4*)&A_log[d*DSTATE + sg*4];
    float a_c[4];
#pragma unroll
    for (int k=0;k<4;++k) a_c[k] = -__expf(al[k]);

    long tbase = (long)b*LL + (long)j*LCH;
    const float*  pd = dtp + tbase*DINNER + d;
    const bf16_t* px = xcp + tbase*DINNER + d;
    const float*  pB = bc  + tbase*32 + sg*4;

    float h[4] = {0.f,0.f,0.f,0.f};
    float sdt = 0.f;
    for (int tt=0; tt<LCH; ++tt){
        float dt = *pd; pd += DINNER;
        float xv = (float)*px; px += DINNER;
        f32x4 Bv = *(const f32x4*)pB; pB += 32;
        float c = dt*xv;
        sdt += dt;
#pragma unroll
        for (int k=0;k<4;++k){
            float da = __expf(dt * a_c[k]);
            h[k] = da*h[k] + c*Bv[k];
        }
    }
    long o = ((long)(b*NCH + j)*DINNER + d)*DSTATE + sg*4;
    f32x4 ap, hv;
#pragma unroll
    for (int k=0;k<4;++k){ ap[k] = __expf(sdt * a_c[k]); hv[k] = h[k]; }
    *(f32x4*)&Aprod[o] = ap;
    *(f32x4*)&Hend[o]  = hv;
}

// pass2: sequential combine; carry-in written IN PLACE into Aprod
__global__ __launch_bounds__(256)
void scan2_k(float* __restrict__ Aprod, const float* __restrict__ Hend)
{
    int idx = blockIdx.x*256 + threadIdx.x;
    if (idx >= BB*DINNER*DSTATE) return;
    int b = idx / (DINNER*DSTATE);
    int ds = idx % (DINNER*DSTATE);
    float h = 0.f;
    for (int j=0;j<NCH;++j){
        long o = (long)(b*NCH+j)*DINNER*DSTATE + ds;
        float ap = Aprod[o];
        float he = Hend[o];
        Aprod[o] = h;
        h = ap*h + he;
    }
}

// pass3: re-scan with carry-in, emit y = (scan_y + Dp*xc)*silu(z) -> bf16
__global__ __launch_bounds__(256)
void scan3_k(const float* __restrict__ dtp, const bf16_t* __restrict__ xcp,
             const float* __restrict__ bc, const float* __restrict__ xz,
             const float* __restrict__ A_log, const float* __restrict__ Dp,
             const float* __restrict__ Hin, bf16_t* __restrict__ yout)
{
    int blk = blockIdx.x;
    int dblk = blk % 12; int tmp = blk / 12;
    int j = tmp % NCH; int b = tmp / NCH;
    int lane = threadIdx.x & 63;
    int wave = threadIdx.x >> 6;
    int d_low = lane & 15;
    int sg = lane >> 4;
    int d = dblk*64 + wave*16 + d_low;

    f32x4 al = *(const f32x4*)&A_log[d*DSTATE + sg*4];
    float a_c[4];
#pragma unroll
    for (int k=0;k<4;++k) a_c[k] = -__expf(al[k]);
    float dpv = Dp[d];

    long o = ((long)(b*NCH + j)*DINNER + d)*DSTATE + sg*4;
    f32x4 hin = *(const f32x4*)&Hin[o];
    float h[4];
#pragma unroll
    for (int k=0;k<4;++k) h[k] = hin[k];

    long tbase = (long)b*LL + (long)j*LCH;
    const float*  pd = dtp + tbase*DINNER + d;
    const bf16_t* px = xcp + tbase*DINNER + d;
    const float*  pB = bc  + tbase*32 + sg*4;
    const float*  pC = bc  + tbase*32 + 16 + sg*4;
    const float*  pz = xz  + tbase*1536 + DINNER + d;
    bf16_t*       py = yout + tbase*DINNER + d;

    for (int tt=0; tt<LCH; ++tt){
        float dt = *pd; pd += DINNER;
        float xv = (float)*px; px += DINNER;
        f32x4 Bv = *(const f32x4*)pB; pB += 32;
        f32x4 Cv = *(const f32x4*)pC; pC += 32;
        float z  = *pz; pz += 1536;
        float c = dt*xv;
        float p = 0.f;
#pragma unroll
        for (int k=0;k<4;++k){
            float da = __expf(dt * a_c[k]);
            h[k] = da*h[k] + c*Bv[k];
            p += h[k]*Cv[k];
        }
        p += __shfl_xor(p, 16);
        p += __shfl_xor(p, 32);
        if (sg == 0){
            float y = (p + dpv*xv) * silu_f(z);
            *py = (bf16_t)y;
        }
        py += DINNER;
    }
}

// ----------------------------------------------------------------------------
extern "C" void kernel_launch(void* const* d_in, const int* in_sizes, int n_in,
                              void* d_out, int out_size, void* d_ws, size_t ws_size,
                              hipStream_t stream)
{
    const float* x       = (const float*)d_in[0];
    const int*   sidx    = (const int*)  d_in[1];
    const float* norm_g  = (const float*)d_in[2];
    const float* norm_b  = (const float*)d_in[3];
    const float* fuse_w1 = (const float*)d_in[4];
    const float* fuse_b1 = (const float*)d_in[5];
    const float* fuse_w2 = (const float*)d_in[6];
    const float* fuse_b2 = (const float*)d_in[7];
    const float* f_in_w   = (const float*)d_in[8];
    const float* f_conv_w = (const float*)d_in[9];
    const float* f_conv_b = (const float*)d_in[10];
    const float* f_xproj  = (const float*)d_in[11];
    const float* f_dt_w   = (const float*)d_in[12];
    const float* f_dt_b   = (const float*)d_in[13];
    const float* f_A_log  = (const float*)d_in[14];
    const float* f_Dp     = (const float*)d_in[15];
    const float* f_out_w  = (const float*)d_in[16];
    const float* b_in_w   = (const float*)d_in[17];
    const float* b_conv_w = (const float*)d_in[18];
    const float* b_conv_b = (const float*)d_in[19];
    const float* b_xproj  = (const float*)d_in[20];
    const float* b_dt_w   = (const float*)d_in[21];
    const float* b_dt_b   = (const float*)d_in[22];
    const float* b_A_log  = (const float*)d_in[23];
    const float* b_Dp     = (const float*)d_in[24];
    const float* b_out_w  = (const float*)d_in[25];
    float* out = (float*)d_out;

    // ---- workspace layout ----
    float* ws    = (float*)d_ws;
    bf16_t* xn   = (bf16_t*)ws;                       // 7,077,888 bf16 = 3,538,944 fl
    float* xz    = ws + 3538944;                      // 14,155,776 fl
    bf16_t* xc   = (bf16_t*)(xz + 14155776);          // 7,077,888 bf16 = 3,538,944 fl
    float* bc    = (float*)(xc + 7077888);            // 294,912 fl (9216 x 32)
    float* dtb   = bc + 294912;                       // 7,077,888 fl
    bf16_t* yb   = (bf16_t*)(dtb + 7077888);          // 7,077,888 bf16 (h1 reuse)
    bf16_t* fused= yb + 7077888;                      // 14,155,776 bf16
    float* Aprod = (float*)(fused + 14155776);        // 1,179,648 fl
    float* Hend  = Aprod + 1179648;                   // 1,179,648 fl
    bf16_t* wbf  = (bf16_t*)(Hend + 1179648);         // 6,537,216 bf16
    bf16_t* h1 = yb;

    bf16_t* w_fin    = wbf + 0;
    bf16_t* w_bin    = wbf + 1179648;
    bf16_t* w_fout   = wbf + 2359296;
    bf16_t* w_bout   = wbf + 2949120;
    bf16_t* w_1      = wbf + 3538944;
    bf16_t* w_2      = wbf + 4718592;
    bf16_t* w_fcombo = wbf + 5308416;   // 800 x 768
    bf16_t* w_bcombo = wbf + 5922816;   // 800 x 768

    // weights -> bf16 (+ xproj B/C rows straight into combo buffers)
    wconv_k<<<20928, 256, 0, stream>>>(f_in_w, b_in_w, f_out_w, b_out_w,
                                       fuse_w1, fuse_w2,
                                       f_xproj + 48*768, b_xproj + 48*768, wbf);
    // combo = dt_w @ xproj[0:48]  (rows 0..767 of combo buffers)
    combo_k<<<768, 256, 0, stream>>>(f_dt_w, f_xproj, w_fcombo);
    combo_k<<<768, 256, 0, stream>>>(b_dt_w, b_xproj, w_bcombo);
    // layernorm -> bf16
    ln_k<<<MTOK, 256, 0, stream>>>(x, norm_g, norm_b, xn);

    dim3 g_in(12, 72);      // 128x128 tiles, N=1536
    dim3 g_cmb(7, 144);     // 64x128 tiles,  N=800
    dim3 g_768(6, 144);     // 64x128 tiles,  N=768
    const int scan_blocks = BB*NCH*12;   // 1152

    // ================= forward direction =================
    gemm2_k<1,0,6,4,4><<<g_in, 256, 0, stream>>>(xn, CC, w_fin, 1536, 768,
                                                 xz, nullptr, 1536, 0, nullptr, nullptr, sidx);
    conv_k<<<27648, 256, 0, stream>>>(xz, f_conv_w, f_conv_b, xc);
    gemm2_k<0,0,5,2,4><<<g_cmb, 256, 0, stream>>>(xc, DINNER, w_fcombo, 800, 768,
                                                  dtb, bc, 768, 0, f_dt_b, nullptr, nullptr);
    scan1_k<<<scan_blocks, 256, 0, stream>>>(dtb, xc, bc, f_A_log, Aprod, Hend);
    scan2_k<<<192, 256, 0, stream>>>(Aprod, Hend);
    scan3_k<<<scan_blocks, 256, 0, stream>>>(dtb, xc, bc, xz, f_A_log, f_Dp, Aprod, yb);
    gemm2_k<0,1,2,2,4><<<g_768, 256, 0, stream>>>(yb, DINNER, w_fout, 768, 768,
                                                  fused, nullptr, 1536, 0, nullptr, nullptr, sidx);

    // ================= backward direction =================
    gemm2_k<2,0,6,4,4><<<g_in, 256, 0, stream>>>(xn, CC, w_bin, 1536, 768,
                                                 xz, nullptr, 1536, 0, nullptr, nullptr, sidx);
    conv_k<<<27648, 256, 0, stream>>>(xz, b_conv_w, b_conv_b, xc);
    gemm2_k<0,0,5,2,4><<<g_cmb, 256, 0, stream>>>(xc, DINNER, w_bcombo, 800, 768,
                                                  dtb, bc, 768, 0, b_dt_b, nullptr, nullptr);
    scan1_k<<<scan_blocks, 256, 0, stream>>>(dtb, xc, bc, b_A_log, Aprod, Hend);
    scan2_k<<<192, 256, 0, stream>>>(Aprod, Hend);
    scan3_k<<<scan_blocks, 256, 0, stream>>>(dtb, xc, bc, xz, b_A_log, b_Dp, Aprod, yb);
    gemm2_k<0,2,2,2,4><<<g_768, 256, 0, stream>>>(yb, DINNER, w_bout, 768, 768,
                                                  fused, nullptr, 1536, 768, nullptr, nullptr, sidx);

    // ================= fusion MLP + residual =================
    gemm2_k<0,0,3,2,4><<<g_768, 256, 0, stream>>>(fused, 1536, w_1, 768, 1536,
                                                  h1, nullptr, 768, 0, fuse_b1, nullptr, nullptr);
    gemm2_k<0,0,4,2,4><<<g_768, 256, 0, stream>>>(h1, DINNER, w_2, 768, 768,
                                                  out, nullptr, 768, 0, fuse_b2, x, nullptr);
}

// Round 4
// 813.729 us; speedup vs baseline: 1.9659x; 1.4855x over previous
//
#include <hip/hip_runtime.h>
#include <hip/hip_bf16.h>
#include <cmath>

#define BB 4
#define LL 2304
#define CC 768
#define DSTATE 16
#define DINNER 768
#define DTRANK 48
#define MTOK (BB*LL)          // 9216
#define NCH 24
#define LCH (LL/NCH)          // 96

typedef __bf16 bf16_t;
typedef __bf16 bf16x8 __attribute__((ext_vector_type(8)));
typedef float  f32x4  __attribute__((ext_vector_type(4)));

__device__ __forceinline__ float silu_f(float v){ return v / (1.0f + __expf(-v)); }

typedef __attribute__((address_space(3))) void  lds_vt;
typedef __attribute__((address_space(1))) void  gbl_vt;
__device__ __forceinline__ void async_copy16(const bf16_t* g, bf16_t* l){
    __builtin_amdgcn_global_load_lds((const gbl_vt*)g, (lds_vt*)l, 16, 0, 0);
}

// ---------------- weight fp32 -> bf16 conversion ----------------------------
// segments: f_in, b_in, f_out, b_out, w1, w2, f_bc(xproj rows 48..79), b_bc
__global__ __launch_bounds__(256)
void wconv_k(const float* __restrict__ a0, const float* __restrict__ a1,
             const float* __restrict__ a2, const float* __restrict__ a3,
             const float* __restrict__ a4, const float* __restrict__ a5,
             const float* __restrict__ a6, const float* __restrict__ a7,
             bf16_t* __restrict__ dst)
{
    const int cum[9]  = {0,1179648,2359296,2949120,3538944,4718592,5308416,5332992,5357568};
    const int dofs[8] = {0,1179648,2359296,2949120,3538944,4718592,5898240,6512640};
    const float* srcs[8] = {a0,a1,a2,a3,a4,a5,a6,a7};
    int idx = blockIdx.x*256 + threadIdx.x;
    if (idx >= 5357568) return;
    int seg = 0;
    while (idx >= cum[seg+1]) ++seg;
    dst[dofs[seg] + idx - cum[seg]] = (bf16_t)srcs[seg][idx - cum[seg]];
}

// ---------------- combo weight: dst[n*768+k] = sum_r dtw[n*48+r]*xproj[r*768+k]
__global__ __launch_bounds__(256)
void combo_k(const float* __restrict__ dtw, const float* __restrict__ xproj,
             bf16_t* __restrict__ dst)
{
    __shared__ float row[48];
    int n = blockIdx.x;
    if (threadIdx.x < 48) row[threadIdx.x] = dtw[n*48 + threadIdx.x];
    __syncthreads();
#pragma unroll
    for (int kk=0; kk<3; ++kk){
        int k = threadIdx.x + 256*kk;
        float s = 0.f;
#pragma unroll 8
        for (int r=0; r<48; ++r) s += row[r]*xproj[r*768 + k];
        dst[n*768 + k] = (bf16_t)s;
    }
}

// ---------------- LayerNorm (per token, C=768) -> bf16 ----------------------
__global__ __launch_bounds__(256)
void ln_k(const float* __restrict__ x, const float* __restrict__ g,
          const float* __restrict__ bta, bf16_t* __restrict__ xn)
{
    int row = blockIdx.x;
    const float* xr = x + (long)row*CC;
    int tid = threadIdx.x;
    float v[3];
#pragma unroll
    for (int r=0;r<3;++r) v[r] = xr[tid + 256*r];
    float s  = v[0]+v[1]+v[2];
    float s2 = v[0]*v[0]+v[1]*v[1]+v[2]*v[2];
    __shared__ float red[8];
    for (int o=32;o;o>>=1){ s += __shfl_down(s,o); s2 += __shfl_down(s2,o); }
    int wv = tid>>6, ln = tid&63;
    if (ln==0){ red[wv]=s; red[4+wv]=s2; }
    __syncthreads();
    if (tid==0){
        red[0] = red[0]+red[1]+red[2]+red[3];
        red[4] = red[4]+red[5]+red[6]+red[7];
    }
    __syncthreads();
    float mu  = red[0]*(1.0f/CC);
    float var = red[4]*(1.0f/CC) - mu*mu;
    float rstd = rsqrtf(var + 1e-6f);
#pragma unroll
    for (int r=0;r<3;++r){
        int c = tid + 256*r;
        xn[(long)row*CC + c] = (bf16_t)((v[r]-mu)*rstd*g[c] + bta[c]);
    }
}

// ---------------- depthwise causal conv (k=4) + silu -> bf16 ----------------
__global__ __launch_bounds__(256)
void conv_k(const bf16_t* __restrict__ xz, const float* __restrict__ cw,
            const float* __restrict__ cb, bf16_t* __restrict__ xc)
{
    int idx = blockIdx.x*256 + threadIdx.x;
    if (idx >= MTOK*DINNER) return;
    int d = idx % DINNER; int row = idx / DINNER;
    int t = row % LL; int b4 = row - t;
    float acc = cb[d];
#pragma unroll
    for (int k=0;k<4;++k){
        int tt = t - 3 + k;
        if (tt >= 0) acc += cw[d*4 + k] * (float)xz[(long)(b4 + tt)*1536 + d];
    }
    xc[idx] = (bf16_t)silu_f(acc);
}

// ---------------- GEMM3: LDS-staged MFMA GEMM, 128x128 tile, BK=64 ----------
// C = A(bf16, opt row-gather) @ W(bf16, NxK)^T
// GATHER/SCATTER: 0 none, 1 fwd (sidx[t]), 2 bwd (sidx[L-1-t])
// EPI: 2 store bf16 | 3 gelu+bias->bf16 | 4 bias+resid->f32 |
//      5 combo split (softplus dt->f32 out1, B/C->f32 out2)
// LDS layout with XOR chunk swizzle: tile row r, 16B chunk c stored at slot
// (r, c^(r&7)) so ds_read_b128 fragment reads are 2-way-per-bank (free).
template<int GATHER, int SCATTER, int EPI>
__global__ __launch_bounds__(256)
void gemm3_k(const bf16_t* __restrict__ A, int lda,
             const bf16_t* __restrict__ W, int N, int K,
             void* __restrict__ out1, void* __restrict__ out2,
             int ldc, int ccol,
             const float* __restrict__ bias,
             const float* __restrict__ resid,
             const int* __restrict__ sidx)
{
    __shared__ __align__(16) bf16_t As[128*64];
    __shared__ __align__(16) bf16_t Bs[128*64];

    const int tid  = threadIdx.x;
    const int lane = tid & 63;
    const int w    = tid >> 6;
    const int ln16 = lane & 15;
    const int q    = lane >> 4;

    const int m0 = blockIdx.y*128;
    const int n0 = blockIdx.x*128;

    // -------- staging source pointers (4 insts/wave for A, 4 for B) --------
    const int srow = lane >> 3;              // row-within-inst-group (0..7)
    const int csrc = (lane & 7) ^ srow;      // global 16B-chunk to fetch (swizzle)
    const bf16_t* gA[4]; const bf16_t* gB[4];
#pragma unroll
    for (int inst=0; inst<4; ++inst){
        int row = w*32 + inst*8 + srow;      // 0..127 tile row
        int r = m0 + row;
        int sr = r;
        if (GATHER != 0){
            int t = r % LL; int bo = r - t;
            sr = bo + ((GATHER==1) ? sidx[t] : sidx[LL-1-t]);
        }
        gA[inst] = A + (long)sr*lda + csrc*8;
        int n = n0 + row; if (n >= N) n = N-1;   // clamp (combo N=800)
        gB[inst] = W + (long)n*K + csrc*8;
    }

    f32x4 acc[4][4];
#pragma unroll
    for (int i=0;i<4;++i)
#pragma unroll
      for (int j=0;j<4;++j) acc[i][j] = (f32x4){0.f,0.f,0.f,0.f};

    const int e = ln16 & 7;                       // read-side swizzle key
    const int ar_base = ((w>>1)*64 + ln16)*64;    // A frag row base (bf16 idx)
    const int br_base = ((w&1)*64 + ln16)*64;     // B frag row base

    for (int k0 = 0; k0 < K; k0 += 64){
#pragma unroll
        for (int inst=0; inst<4; ++inst){
            bf16_t* la = As + (w*256 + inst*64)*8;
            bf16_t* lb = Bs + (w*256 + inst*64)*8;
            async_copy16(gA[inst] + k0, la);
            async_copy16(gB[inst] + k0, lb);
        }
        __syncthreads();
#pragma unroll
        for (int kk=0; kk<2; ++kk){
            const int ce = (((kk<<2)|q) ^ e)*8;
            bf16x8 af[4], bf[4];
#pragma unroll
            for (int i=0;i<4;++i) af[i] = *(const bf16x8*)&As[ar_base + i*16*64 + ce];
#pragma unroll
            for (int j=0;j<4;++j) bf[j] = *(const bf16x8*)&Bs[br_base + j*16*64 + ce];
#pragma unroll
            for (int i=0;i<4;++i)
#pragma unroll
              for (int j=0;j<4;++j)
                acc[i][j] = __builtin_amdgcn_mfma_f32_16x16x32_bf16(af[i], bf[j], acc[i][j], 0,0,0);
        }
        __syncthreads();
    }

    const int mw = m0 + (w>>1)*64;
    const int nw = n0 + (w&1)*64;
#pragma unroll
    for (int i=0;i<4;++i){
#pragma unroll
        for (int reg=0; reg<4; ++reg){
            int r = mw + i*16 + q*4 + reg;
            int orow = r;
            if (SCATTER != 0){
                int t = r % LL; int bo = r - t;
                orow = bo + ((SCATTER==1) ? sidx[t] : sidx[LL-1-t]);
            }
#pragma unroll
            for (int j=0;j<4;++j){
                int col = nw + j*16 + ln16;
                if (col >= N) continue;
                float v = acc[i][j][reg];
                if (EPI==2){
                    ((bf16_t*)out1)[(long)orow*ldc + ccol + col] = (bf16_t)v;
                } else if (EPI==3){
                    v += bias[col];
                    v = 0.5f*v*(1.0f + erff(v*0.70710678118654752f));
                    ((bf16_t*)out1)[(long)orow*ldc + col] = (bf16_t)v;
                } else if (EPI==4){
                    v += bias[col] + resid[(long)r*CC + col];
                    ((float*)out1)[(long)orow*ldc + col] = v;
                } else if (EPI==5){
                    if (col < 768){
                        v += bias[col];
                        v = fmaxf(v,0.f) + log1pf(__expf(-fabsf(v)));
                        ((float*)out1)[(long)r*768 + col] = v;
                    } else {
                        ((float*)out2)[(long)r*32 + (col-768)] = v;
                    }
                }
            }
        }
    }
}

// ---------------- chunked selective scan ------------------------------------
__global__ __launch_bounds__(256)
void scan1_k(const float* __restrict__ dtp, const bf16_t* __restrict__ xcp,
             const float* __restrict__ bc, const float* __restrict__ A_log,
             float* __restrict__ Aprod, float* __restrict__ Hend)
{
    int blk = blockIdx.x;
    int dblk = blk % 12; int tmp = blk / 12;
    int j = tmp % NCH; int b = tmp / NCH;
    int lane = threadIdx.x & 63;
    int wave = threadIdx.x >> 6;
    int d_low = lane & 15;
    int sg = lane >> 4;
    int d = dblk*64 + wave*16 + d_low;

    f32x4 al = *(const f32x4*)&A_log[d*DSTATE + sg*4];
    float a_c[4];
#pragma unroll
    for (int k=0;k<4;++k) a_c[k] = -__expf(al[k]);

    long tbase = (long)b*LL + (long)j*LCH;
    const float*  pd = dtp + tbase*DINNER + d;
    const bf16_t* px = xcp + tbase*DINNER + d;
    const float*  pB = bc  + tbase*32 + sg*4;

    float h[4] = {0.f,0.f,0.f,0.f};
    float sdt = 0.f;
    for (int tt=0; tt<LCH; ++tt){
        float dt = *pd; pd += DINNER;
        float xv = (float)*px; px += DINNER;
        f32x4 Bv = *(const f32x4*)pB; pB += 32;
        float c = dt*xv;
        sdt += dt;
#pragma unroll
        for (int k=0;k<4;++k){
            float da = __expf(dt * a_c[k]);
            h[k] = da*h[k] + c*Bv[k];
        }
    }
    long o = ((long)(b*NCH + j)*DINNER + d)*DSTATE + sg*4;
    f32x4 ap, hv;
#pragma unroll
    for (int k=0;k<4;++k){ ap[k] = __expf(sdt * a_c[k]); hv[k] = h[k]; }
    *(f32x4*)&Aprod[o] = ap;
    *(f32x4*)&Hend[o]  = hv;
}

__global__ __launch_bounds__(256)
void scan2_k(float* __restrict__ Aprod, const float* __restrict__ Hend)
{
    int idx = blockIdx.x*256 + threadIdx.x;
    if (idx >= BB*DINNER*DSTATE) return;
    int b = idx / (DINNER*DSTATE);
    int ds = idx % (DINNER*DSTATE);
    float h = 0.f;
    for (int j=0;j<NCH;++j){
        long o = (long)(b*NCH+j)*DINNER*DSTATE + ds;
        float ap = Aprod[o];
        float he = Hend[o];
        Aprod[o] = h;
        h = ap*h + he;
    }
}

__global__ __launch_bounds__(256)
void scan3_k(const float* __restrict__ dtp, const bf16_t* __restrict__ xcp,
             const float* __restrict__ bc, const bf16_t* __restrict__ xz,
             const float* __restrict__ A_log, const float* __restrict__ Dp,
             const float* __restrict__ Hin, bf16_t* __restrict__ yout)
{
    int blk = blockIdx.x;
    int dblk = blk % 12; int tmp = blk / 12;
    int j = tmp % NCH; int b = tmp / NCH;
    int lane = threadIdx.x & 63;
    int wave = threadIdx.x >> 6;
    int d_low = lane & 15;
    int sg = lane >> 4;
    int d = dblk*64 + wave*16 + d_low;

    f32x4 al = *(const f32x4*)&A_log[d*DSTATE + sg*4];
    float a_c[4];
#pragma unroll
    for (int k=0;k<4;++k) a_c[k] = -__expf(al[k]);
    float dpv = Dp[d];

    long o = ((long)(b*NCH + j)*DINNER + d)*DSTATE + sg*4;
    f32x4 hin = *(const f32x4*)&Hin[o];
    float h[4];
#pragma unroll
    for (int k=0;k<4;++k) h[k] = hin[k];

    long tbase = (long)b*LL + (long)j*LCH;
    const float*  pd = dtp + tbase*DINNER + d;
    const bf16_t* px = xcp + tbase*DINNER + d;
    const float*  pB = bc  + tbase*32 + sg*4;
    const float*  pC = bc  + tbase*32 + 16 + sg*4;
    const bf16_t* pz = xz  + tbase*1536 + DINNER + d;
    bf16_t*       py = yout + tbase*DINNER + d;

    for (int tt=0; tt<LCH; ++tt){
        float dt = *pd; pd += DINNER;
        float xv = (float)*px; px += DINNER;
        f32x4 Bv = *(const f32x4*)pB; pB += 32;
        f32x4 Cv = *(const f32x4*)pC; pC += 32;
        float z  = (float)*pz; pz += 1536;
        float c = dt*xv;
        float p = 0.f;
#pragma unroll
        for (int k=0;k<4;++k){
            float da = __expf(dt * a_c[k]);
            h[k] = da*h[k] + c*Bv[k];
            p += h[k]*Cv[k];
        }
        p += __shfl_xor(p, 16);
        p += __shfl_xor(p, 32);
        if (sg == 0){
            float y = (p + dpv*xv) * silu_f(z);
            *py = (bf16_t)y;
        }
        py += DINNER;
    }
}

// ----------------------------------------------------------------------------
extern "C" void kernel_launch(void* const* d_in, const int* in_sizes, int n_in,
                              void* d_out, int out_size, void* d_ws, size_t ws_size,
                              hipStream_t stream)
{
    const float* x       = (const float*)d_in[0];
    const int*   sidx    = (const int*)  d_in[1];
    const float* norm_g  = (const float*)d_in[2];
    const float* norm_b  = (const float*)d_in[3];
    const float* fuse_w1 = (const float*)d_in[4];
    const float* fuse_b1 = (const float*)d_in[5];
    const float* fuse_w2 = (const float*)d_in[6];
    const float* fuse_b2 = (const float*)d_in[7];
    const float* f_in_w   = (const float*)d_in[8];
    const float* f_conv_w = (const float*)d_in[9];
    const float* f_conv_b = (const float*)d_in[10];
    const float* f_xproj  = (const float*)d_in[11];
    const float* f_dt_w   = (const float*)d_in[12];
    const float* f_dt_b   = (const float*)d_in[13];
    const float* f_A_log  = (const float*)d_in[14];
    const float* f_Dp     = (const float*)d_in[15];
    const float* f_out_w  = (const float*)d_in[16];
    const float* b_in_w   = (const float*)d_in[17];
    const float* b_conv_w = (const float*)d_in[18];
    const float* b_conv_b = (const float*)d_in[19];
    const float* b_xproj  = (const float*)d_in[20];
    const float* b_dt_w   = (const float*)d_in[21];
    const float* b_dt_b   = (const float*)d_in[22];
    const float* b_A_log  = (const float*)d_in[23];
    const float* b_Dp     = (const float*)d_in[24];
    const float* b_out_w  = (const float*)d_in[25];
    float* out = (float*)d_out;

    // ---- workspace layout (float units) ----
    float* ws    = (float*)d_ws;
    bf16_t* xn   = (bf16_t*)ws;                       // 7,077,888 bf16
    bf16_t* xz   = (bf16_t*)(ws + 3538944);           // 14,155,776 bf16
    bf16_t* xc   = (bf16_t*)(ws + 3538944 + 7077888); // 7,077,888 bf16
    float* bc    = ws + 3538944 + 7077888 + 3538944;  // 294,912 fl
    float* dtb   = bc + 294912;                       // 7,077,888 fl
    bf16_t* yb   = (bf16_t*)(dtb + 7077888);          // 7,077,888 bf16 (h1 reuse)
    bf16_t* fused= yb + 7077888;                      // 14,155,776 bf16
    float* Aprod = (float*)(fused + 14155776);        // 1,179,648 fl
    float* Hend  = Aprod + 1179648;                   // 1,179,648 fl
    bf16_t* wbf  = (bf16_t*)(Hend + 1179648);         // 6,537,216 bf16
    bf16_t* h1 = yb;

    bf16_t* w_fin    = wbf + 0;
    bf16_t* w_bin    = wbf + 1179648;
    bf16_t* w_fout   = wbf + 2359296;
    bf16_t* w_bout   = wbf + 2949120;
    bf16_t* w_1      = wbf + 3538944;
    bf16_t* w_2      = wbf + 4718592;
    bf16_t* w_fcombo = wbf + 5308416;   // 800 x 768
    bf16_t* w_bcombo = wbf + 5922816;   // 800 x 768

    wconv_k<<<20928, 256, 0, stream>>>(f_in_w, b_in_w, f_out_w, b_out_w,
                                       fuse_w1, fuse_w2,
                                       f_xproj + 48*768, b_xproj + 48*768, wbf);
    combo_k<<<768, 256, 0, stream>>>(f_dt_w, f_xproj, w_fcombo);
    combo_k<<<768, 256, 0, stream>>>(b_dt_w, b_xproj, w_bcombo);
    ln_k<<<MTOK, 256, 0, stream>>>(x, norm_g, norm_b, xn);

    dim3 g_in(12, 72);      // N=1536
    dim3 g_cmb(7, 72);      // N=800 (clamped staging)
    dim3 g_768(6, 72);      // N=768
    const int scan_blocks = BB*NCH*12;   // 1152

    // ================= forward direction =================
    gemm3_k<1,0,2><<<g_in, 256, 0, stream>>>(xn, CC, w_fin, 1536, 768,
                                             xz, nullptr, 1536, 0, nullptr, nullptr, sidx);
    conv_k<<<27648, 256, 0, stream>>>(xz, f_conv_w, f_conv_b, xc);
    gemm3_k<0,0,5><<<g_cmb, 256, 0, stream>>>(xc, DINNER, w_fcombo, 800, 768,
                                              dtb, bc, 768, 0, f_dt_b, nullptr, nullptr);
    scan1_k<<<scan_blocks, 256, 0, stream>>>(dtb, xc, bc, f_A_log, Aprod, Hend);
    scan2_k<<<192, 256, 0, stream>>>(Aprod, Hend);
    scan3_k<<<scan_blocks, 256, 0, stream>>>(dtb, xc, bc, xz, f_A_log, f_Dp, Aprod, yb);
    gemm3_k<0,1,2><<<g_768, 256, 0, stream>>>(yb, DINNER, w_fout, 768, 768,
                                              fused, nullptr, 1536, 0, nullptr, nullptr, sidx);

    // ================= backward direction =================
    gemm3_k<2,0,2><<<g_in, 256, 0, stream>>>(xn, CC, w_bin, 1536, 768,
                                             xz, nullptr, 1536, 0, nullptr, nullptr, sidx);
    conv_k<<<27648, 256, 0, stream>>>(xz, b_conv_w, b_conv_b, xc);
    gemm3_k<0,0,5><<<g_cmb, 256, 0, stream>>>(xc, DINNER, w_bcombo, 800, 768,
                                              dtb, bc, 768, 0, b_dt_b, nullptr, nullptr);
    scan1_k<<<scan_blocks, 256, 0, stream>>>(dtb, xc, bc, b_A_log, Aprod, Hend);
    scan2_k<<<192, 256, 0, stream>>>(Aprod, Hend);
    scan3_k<<<scan_blocks, 256, 0, stream>>>(dtb, xc, bc, xz, b_A_log, b_Dp, Aprod, yb);
    gemm3_k<0,2,2><<<g_768, 256, 0, stream>>>(yb, DINNER, w_bout, 768, 768,
                                              fused, nullptr, 1536, 768, nullptr, nullptr, sidx);

    // ================= fusion MLP + residual =================
    gemm3_k<0,0,3><<<g_768, 256, 0, stream>>>(fused, 1536, w_1, 768, 1536,
                                              h1, nullptr, 768, 0, fuse_b1, nullptr, nullptr);
    gemm3_k<0,0,4><<<g_768, 256, 0, stream>>>(h1, DINNER, w_2, 768, 768,
                                              out, nullptr, 768, 0, fuse_b2, x, nullptr);
}

// Round 5
// 726.365 us; speedup vs baseline: 2.2024x; 1.1203x over previous
//
#include <hip/hip_runtime.h>
#include <hip/hip_bf16.h>
#include <cmath>

#define BB 4
#define LL 2304
#define CC 768
#define DSTATE 16
#define DINNER 768
#define DTRANK 48
#define MTOK (BB*LL)          // 9216
#define NCH 48
#define LCH (LL/NCH)          // 48

typedef __bf16 bf16_t;
typedef __bf16 bf16x8 __attribute__((ext_vector_type(8)));
typedef float  f32x4  __attribute__((ext_vector_type(4)));

__device__ __forceinline__ float silu_f(float v){ return v / (1.0f + __expf(-v)); }

typedef __attribute__((address_space(3))) void  lds_vt;
typedef __attribute__((address_space(1))) void  gbl_vt;
__device__ __forceinline__ void async_copy16(const void* g, void* l){
    __builtin_amdgcn_global_load_lds((const gbl_vt*)g, (lds_vt*)l, 16, 0, 0);
}

// ---------------- weight fp32 -> bf16 conversion ----------------------------
// segments: f_in, b_in, f_out, b_out, w1, w2, f_bc(xproj rows 48..79), b_bc
__global__ __launch_bounds__(256)
void wconv_k(const float* __restrict__ a0, const float* __restrict__ a1,
             const float* __restrict__ a2, const float* __restrict__ a3,
             const float* __restrict__ a4, const float* __restrict__ a5,
             const float* __restrict__ a6, const float* __restrict__ a7,
             bf16_t* __restrict__ dst)
{
    const int cum[9]  = {0,1179648,2359296,2949120,3538944,4718592,5308416,5332992,5357568};
    const int dofs[8] = {0,1179648,2359296,2949120,3538944,4718592,5898240,6512640};
    const float* srcs[8] = {a0,a1,a2,a3,a4,a5,a6,a7};
    int idx = blockIdx.x*256 + threadIdx.x;
    if (idx >= 5357568) return;
    int seg = 0;
    while (idx >= cum[seg+1]) ++seg;
    dst[dofs[seg] + idx - cum[seg]] = (bf16_t)srcs[seg][idx - cum[seg]];
}

// ---------------- combo weight: dst[n*768+k] = sum_r dtw[n*48+r]*xproj[r*768+k]
__global__ __launch_bounds__(256)
void combo_k(const float* __restrict__ dtw, const float* __restrict__ xproj,
             bf16_t* __restrict__ dst)
{
    __shared__ float row[48];
    int n = blockIdx.x;
    if (threadIdx.x < 48) row[threadIdx.x] = dtw[n*48 + threadIdx.x];
    __syncthreads();
#pragma unroll
    for (int kk=0; kk<3; ++kk){
        int k = threadIdx.x + 256*kk;
        float s = 0.f;
#pragma unroll 8
        for (int r=0; r<48; ++r) s += row[r]*xproj[r*768 + k];
        dst[n*768 + k] = (bf16_t)s;
    }
}

// ---------------- LayerNorm (per token, C=768) -> bf16 ----------------------
__global__ __launch_bounds__(256)
void ln_k(const float* __restrict__ x, const float* __restrict__ g,
          const float* __restrict__ bta, bf16_t* __restrict__ xn)
{
    int row = blockIdx.x;
    const float* xr = x + (long)row*CC;
    int tid = threadIdx.x;
    float v[3];
#pragma unroll
    for (int r=0;r<3;++r) v[r] = xr[tid + 256*r];
    float s  = v[0]+v[1]+v[2];
    float s2 = v[0]*v[0]+v[1]*v[1]+v[2]*v[2];
    __shared__ float red[8];
    for (int o=32;o;o>>=1){ s += __shfl_down(s,o); s2 += __shfl_down(s2,o); }
    int wv = tid>>6, ln = tid&63;
    if (ln==0){ red[wv]=s; red[4+wv]=s2; }
    __syncthreads();
    if (tid==0){
        red[0] = red[0]+red[1]+red[2]+red[3];
        red[4] = red[4]+red[5]+red[6]+red[7];
    }
    __syncthreads();
    float mu  = red[0]*(1.0f/CC);
    float var = red[4]*(1.0f/CC) - mu*mu;
    float rstd = rsqrtf(var + 1e-6f);
#pragma unroll
    for (int r=0;r<3;++r){
        int c = tid + 256*r;
        xn[(long)row*CC + c] = (bf16_t)((v[r]-mu)*rstd*g[c] + bta[c]);
    }
}

// ---------------- depthwise causal conv (k=4) + silu -> bf16 ----------------
__global__ __launch_bounds__(256)
void conv_k(const bf16_t* __restrict__ xz, const float* __restrict__ cw,
            const float* __restrict__ cb, bf16_t* __restrict__ xc)
{
    int idx = blockIdx.x*256 + threadIdx.x;
    if (idx >= MTOK*DINNER) return;
    int d = idx % DINNER; int row = idx / DINNER;
    int t = row % LL; int b4 = row - t;
    float acc = cb[d];
#pragma unroll
    for (int k=0;k<4;++k){
        int tt = t - 3 + k;
        if (tt >= 0) acc += cw[d*4 + k] * (float)xz[(long)(b4 + tt)*1536 + d];
    }
    xc[idx] = (bf16_t)silu_f(acc);
}

// ---------------- GEMM3: LDS-staged MFMA GEMM, 128x128 tile, BK=64 ----------
// (unchanged from round 4)
template<int GATHER, int SCATTER, int EPI>
__global__ __launch_bounds__(256)
void gemm3_k(const bf16_t* __restrict__ A, int lda,
             const bf16_t* __restrict__ W, int N, int K,
             void* __restrict__ out1, void* __restrict__ out2,
             int ldc, int ccol,
             const float* __restrict__ bias,
             const float* __restrict__ resid,
             const int* __restrict__ sidx)
{
    __shared__ __align__(16) bf16_t As[128*64];
    __shared__ __align__(16) bf16_t Bs[128*64];

    const int tid  = threadIdx.x;
    const int lane = tid & 63;
    const int w    = tid >> 6;
    const int ln16 = lane & 15;
    const int q    = lane >> 4;

    const int m0 = blockIdx.y*128;
    const int n0 = blockIdx.x*128;

    const int srow = lane >> 3;
    const int csrc = (lane & 7) ^ srow;
    const bf16_t* gA[4]; const bf16_t* gB[4];
#pragma unroll
    for (int inst=0; inst<4; ++inst){
        int row = w*32 + inst*8 + srow;
        int r = m0 + row;
        int sr = r;
        if (GATHER != 0){
            int t = r % LL; int bo = r - t;
            sr = bo + ((GATHER==1) ? sidx[t] : sidx[LL-1-t]);
        }
        gA[inst] = A + (long)sr*lda + csrc*8;
        int n = n0 + row; if (n >= N) n = N-1;
        gB[inst] = W + (long)n*K + csrc*8;
    }

    f32x4 acc[4][4];
#pragma unroll
    for (int i=0;i<4;++i)
#pragma unroll
      for (int j=0;j<4;++j) acc[i][j] = (f32x4){0.f,0.f,0.f,0.f};

    const int e = ln16 & 7;
    const int ar_base = ((w>>1)*64 + ln16)*64;
    const int br_base = ((w&1)*64 + ln16)*64;

    for (int k0 = 0; k0 < K; k0 += 64){
#pragma unroll
        for (int inst=0; inst<4; ++inst){
            bf16_t* la = As + (w*256 + inst*64)*8;
            bf16_t* lb = Bs + (w*256 + inst*64)*8;
            async_copy16(gA[inst] + k0, la);
            async_copy16(gB[inst] + k0, lb);
        }
        __syncthreads();
#pragma unroll
        for (int kk=0; kk<2; ++kk){
            const int ce = (((kk<<2)|q) ^ e)*8;
            bf16x8 af[4], bf[4];
#pragma unroll
            for (int i=0;i<4;++i) af[i] = *(const bf16x8*)&As[ar_base + i*16*64 + ce];
#pragma unroll
            for (int j=0;j<4;++j) bf[j] = *(const bf16x8*)&Bs[br_base + j*16*64 + ce];
#pragma unroll
            for (int i=0;i<4;++i)
#pragma unroll
              for (int j=0;j<4;++j)
                acc[i][j] = __builtin_amdgcn_mfma_f32_16x16x32_bf16(af[i], bf[j], acc[i][j], 0,0,0);
        }
        __syncthreads();
    }

    const int mw = m0 + (w>>1)*64;
    const int nw = n0 + (w&1)*64;
#pragma unroll
    for (int i=0;i<4;++i){
#pragma unroll
        for (int reg=0; reg<4; ++reg){
            int r = mw + i*16 + q*4 + reg;
            int orow = r;
            if (SCATTER != 0){
                int t = r % LL; int bo = r - t;
                orow = bo + ((SCATTER==1) ? sidx[t] : sidx[LL-1-t]);
            }
#pragma unroll
            for (int j=0;j<4;++j){
                int col = nw + j*16 + ln16;
                if (col >= N) continue;
                float v = acc[i][j][reg];
                if (EPI==2){
                    ((bf16_t*)out1)[(long)orow*ldc + ccol + col] = (bf16_t)v;
                } else if (EPI==3){
                    v += bias[col];
                    v = 0.5f*v*(1.0f + erff(v*0.70710678118654752f));
                    ((bf16_t*)out1)[(long)orow*ldc + col] = (bf16_t)v;
                } else if (EPI==4){
                    v += bias[col] + resid[(long)r*CC + col];
                    ((float*)out1)[(long)orow*ldc + col] = v;
                } else if (EPI==5){
                    if (col < 768){
                        v += bias[col];
                        v = fmaxf(v,0.f) + log1pf(__expf(-fabsf(v)));
                        ((float*)out1)[(long)r*768 + col] = v;
                    } else {
                        ((float*)out2)[(long)r*32 + (col-768)] = v;
                    }
                }
            }
        }
    }
}

// ---------------- LDS-staged chunked selective scan -------------------------
// Block: 256 thr = 4 waves; tile = 64 d x LCH(=48) t.
// Thread: d_local = wave*16 + (lane&15), owns s = (lane>>4)*4 .. +3.
// Dynamic LDS: [dt f32 48x64 | xc bf16 48x64 | bc f32 48x32 | z bf16 | y bf16]
// PASS 1: local scan -> Aprod=exp(a*sum_dt), Hend.  PASS 3: re-scan + emit y.
template<int PASS>
__global__ __launch_bounds__(256)
void scanp_k(const float* __restrict__ dtp, const bf16_t* __restrict__ xcp,
             const float* __restrict__ bcp, const bf16_t* __restrict__ xzp,
             const float* __restrict__ A_log, const float* __restrict__ Dp,
             const float* __restrict__ Hin, float* __restrict__ Aprod,
             float* __restrict__ Hend, bf16_t* __restrict__ yout)
{
    extern __shared__ __align__(16) char smem[];
    float*  s_dt = (float*) smem;            // 12288 B
    bf16_t* s_xc = (bf16_t*)(smem + 12288);  //  6144 B
    float*  s_bc = (float*) (smem + 18432);  //  6144 B
    bf16_t* s_z  = (bf16_t*)(smem + 24576);  //  6144 B (PASS 3)
    bf16_t* s_y  = (bf16_t*)(smem + 30720);  //  6144 B (PASS 3)

    int blk = blockIdx.x;
    int dblk = blk % 12; int tmp = blk / 12;
    int j = tmp % NCH; int b = tmp / NCH;
    int tid = threadIdx.x;
    long tbase = (long)b*LL + (long)j*LCH;

    // ---- stage tiles (coalesced 16B async copies) ----
    const float* gdt = dtp + tbase*DINNER + dblk*64;
#pragma unroll
    for (int i=0;i<3;++i){
        int c = tid + 256*i; int t = c>>4, dc = c&15;
        async_copy16(gdt + (long)t*DINNER + dc*4, s_dt + c*4);
    }
    const bf16_t* gxc = xcp + tbase*DINNER + dblk*64;
    {
        int c = tid; int t=c>>3, dc=c&7;
        async_copy16(gxc + (long)t*DINNER + dc*8, s_xc + c*8);
        if (tid < 128){ c = tid+256; t=c>>3; dc=c&7;
            async_copy16(gxc + (long)t*DINNER + dc*8, s_xc + c*8); }
    }
    const float* gbc = bcp + tbase*32;
    {
        int c = tid; int t=c>>3, dc=c&7;
        async_copy16(gbc + (long)t*32 + dc*4, s_bc + c*4);
        if (tid < 128){ c = tid+256; t=c>>3; dc=c&7;
            async_copy16(gbc + (long)t*32 + dc*4, s_bc + c*4); }
    }
    if (PASS==3){
        const bf16_t* gz = xzp + tbase*1536 + DINNER + dblk*64;
        int c = tid; int t=c>>3, dc=c&7;
        async_copy16(gz + (long)t*1536 + dc*8, s_z + c*8);
        if (tid < 128){ c = tid+256; t=c>>3; dc=c&7;
            async_copy16(gz + (long)t*1536 + dc*8, s_z + c*8); }
    }
    __syncthreads();

    // ---- compute ----
    int lane = tid & 63, w = tid >> 6;
    int d_low = lane & 15, sg = lane >> 4;
    int dl = w*16 + d_low;
    int d  = dblk*64 + dl;

    f32x4 al = *(const f32x4*)&A_log[d*DSTATE + sg*4];
    float a_c[4];
#pragma unroll
    for (int k=0;k<4;++k) a_c[k] = -__expf(al[k]);

    float h[4] = {0.f,0.f,0.f,0.f};
    float dpv = 0.f;
    long o = ((long)(b*NCH + j)*DINNER + d)*DSTATE + sg*4;
    if (PASS==3){
        f32x4 hin = *(const f32x4*)&Hin[o];
#pragma unroll
        for (int k=0;k<4;++k) h[k] = hin[k];
        dpv = Dp[d];
    }
    float sdt = 0.f;

    for (int t=0; t<LCH; ++t){
        float dt = s_dt[t*64 + dl];
        float xv = (float)s_xc[t*64 + dl];
        f32x4 Bv = *(const f32x4*)&s_bc[t*32 + sg*4];
        float c = dt*xv;
        if (PASS==1) sdt += dt;
#pragma unroll
        for (int k=0;k<4;++k){
            float da = __expf(dt * a_c[k]);
            h[k] = da*h[k] + c*Bv[k];
        }
        if (PASS==3){
            f32x4 Cv = *(const f32x4*)&s_bc[t*32 + 16 + sg*4];
            float p = h[0]*Cv[0] + h[1]*Cv[1] + h[2]*Cv[2] + h[3]*Cv[3];
            p += __shfl_xor(p, 16);
            p += __shfl_xor(p, 32);
            if (sg == 0){
                float z = (float)s_z[t*64 + dl];
                s_y[t*64 + dl] = (bf16_t)((p + dpv*xv) * silu_f(z));
            }
        }
    }

    if (PASS==1){
        f32x4 ap, hv;
#pragma unroll
        for (int k=0;k<4;++k){ ap[k] = __expf(sdt * a_c[k]); hv[k] = h[k]; }
        *(f32x4*)&Aprod[o] = ap;
        *(f32x4*)&Hend[o]  = hv;
    }
    if (PASS==3){
        __syncthreads();
        bf16_t* gy = yout + tbase*DINNER + dblk*64;
        int c = tid; int t=c>>3, dc=c&7;
        *(int4*)(gy + (long)t*DINNER + dc*8) = *(const int4*)&s_y[c*8];
        if (tid < 128){ c = tid+256; t=c>>3; dc=c&7;
            *(int4*)(gy + (long)t*DINNER + dc*8) = *(const int4*)&s_y[c*8]; }
    }
}

// pass2: sequential combine; carry-in written IN PLACE into Aprod
__global__ __launch_bounds__(256)
void scan2_k(float* __restrict__ Aprod, const float* __restrict__ Hend)
{
    int idx = blockIdx.x*256 + threadIdx.x;
    if (idx >= BB*DINNER*DSTATE) return;
    int b = idx / (DINNER*DSTATE);
    int ds = idx % (DINNER*DSTATE);
    float h = 0.f;
    for (int j=0;j<NCH;++j){
        long o = (long)(b*NCH+j)*DINNER*DSTATE + ds;
        float ap = Aprod[o];
        float he = Hend[o];
        Aprod[o] = h;
        h = ap*h + he;
    }
}

// ----------------------------------------------------------------------------
extern "C" void kernel_launch(void* const* d_in, const int* in_sizes, int n_in,
                              void* d_out, int out_size, void* d_ws, size_t ws_size,
                              hipStream_t stream)
{
    const float* x       = (const float*)d_in[0];
    const int*   sidx    = (const int*)  d_in[1];
    const float* norm_g  = (const float*)d_in[2];
    const float* norm_b  = (const float*)d_in[3];
    const float* fuse_w1 = (const float*)d_in[4];
    const float* fuse_b1 = (const float*)d_in[5];
    const float* fuse_w2 = (const float*)d_in[6];
    const float* fuse_b2 = (const float*)d_in[7];
    const float* f_in_w   = (const float*)d_in[8];
    const float* f_conv_w = (const float*)d_in[9];
    const float* f_conv_b = (const float*)d_in[10];
    const float* f_xproj  = (const float*)d_in[11];
    const float* f_dt_w   = (const float*)d_in[12];
    const float* f_dt_b   = (const float*)d_in[13];
    const float* f_A_log  = (const float*)d_in[14];
    const float* f_Dp     = (const float*)d_in[15];
    const float* f_out_w  = (const float*)d_in[16];
    const float* b_in_w   = (const float*)d_in[17];
    const float* b_conv_w = (const float*)d_in[18];
    const float* b_conv_b = (const float*)d_in[19];
    const float* b_xproj  = (const float*)d_in[20];
    const float* b_dt_w   = (const float*)d_in[21];
    const float* b_dt_b   = (const float*)d_in[22];
    const float* b_A_log  = (const float*)d_in[23];
    const float* b_Dp     = (const float*)d_in[24];
    const float* b_out_w  = (const float*)d_in[25];
    float* out = (float*)d_out;

    // ---- workspace layout (float units) ----
    float* ws    = (float*)d_ws;
    bf16_t* xn   = (bf16_t*)ws;                       // 7,077,888 bf16
    bf16_t* xz   = (bf16_t*)(ws + 3538944);           // 14,155,776 bf16
    bf16_t* xc   = (bf16_t*)(ws + 3538944 + 7077888); // 7,077,888 bf16
    float* bc    = ws + 3538944 + 7077888 + 3538944;  // 294,912 fl
    float* dtb   = bc + 294912;                       // 7,077,888 fl
    bf16_t* yb   = (bf16_t*)(dtb + 7077888);          // 7,077,888 bf16 (h1 reuse)
    bf16_t* fused= yb + 7077888;                      // 14,155,776 bf16
    float* Aprod = (float*)(fused + 14155776);        // 2,359,296 fl (NCH=48)
    float* Hend  = Aprod + 2359296;                   // 2,359,296 fl
    bf16_t* wbf  = (bf16_t*)(Hend + 2359296);         // 6,537,216 bf16
    bf16_t* h1 = yb;

    bf16_t* w_fin    = wbf + 0;
    bf16_t* w_bin    = wbf + 1179648;
    bf16_t* w_fout   = wbf + 2359296;
    bf16_t* w_bout   = wbf + 2949120;
    bf16_t* w_1      = wbf + 3538944;
    bf16_t* w_2      = wbf + 4718592;
    bf16_t* w_fcombo = wbf + 5308416;   // 800 x 768
    bf16_t* w_bcombo = wbf + 5922816;   // 800 x 768

    wconv_k<<<20928, 256, 0, stream>>>(f_in_w, b_in_w, f_out_w, b_out_w,
                                       fuse_w1, fuse_w2,
                                       f_xproj + 48*768, b_xproj + 48*768, wbf);
    combo_k<<<768, 256, 0, stream>>>(f_dt_w, f_xproj, w_fcombo);
    combo_k<<<768, 256, 0, stream>>>(b_dt_w, b_xproj, w_bcombo);
    ln_k<<<MTOK, 256, 0, stream>>>(x, norm_g, norm_b, xn);

    dim3 g_in(12, 72);      // N=1536
    dim3 g_cmb(7, 72);      // N=800 (clamped staging)
    dim3 g_768(6, 72);      // N=768
    const int scan_blocks = BB*NCH*12;   // 2304
    const unsigned lds1 = 24576, lds3 = 36864;

    // ================= forward direction =================
    gemm3_k<1,0,2><<<g_in, 256, 0, stream>>>(xn, CC, w_fin, 1536, 768,
                                             xz, nullptr, 1536, 0, nullptr, nullptr, sidx);
    conv_k<<<27648, 256, 0, stream>>>(xz, f_conv_w, f_conv_b, xc);
    gemm3_k<0,0,5><<<g_cmb, 256, 0, stream>>>(xc, DINNER, w_fcombo, 800, 768,
                                              dtb, bc, 768, 0, f_dt_b, nullptr, nullptr);
    scanp_k<1><<<scan_blocks, 256, lds1, stream>>>(dtb, xc, bc, nullptr,
                                                   f_A_log, nullptr, nullptr, Aprod, Hend, nullptr);
    scan2_k<<<192, 256, 0, stream>>>(Aprod, Hend);
    scanp_k<3><<<scan_blocks, 256, lds3, stream>>>(dtb, xc, bc, xz,
                                                   f_A_log, f_Dp, Aprod, nullptr, nullptr, yb);
    gemm3_k<0,1,2><<<g_768, 256, 0, stream>>>(yb, DINNER, w_fout, 768, 768,
                                              fused, nullptr, 1536, 0, nullptr, nullptr, sidx);

    // ================= backward direction =================
    gemm3_k<2,0,2><<<g_in, 256, 0, stream>>>(xn, CC, w_bin, 1536, 768,
                                             xz, nullptr, 1536, 0, nullptr, nullptr, sidx);
    conv_k<<<27648, 256, 0, stream>>>(xz, b_conv_w, b_conv_b, xc);
    gemm3_k<0,0,5><<<g_cmb, 256, 0, stream>>>(xc, DINNER, w_bcombo, 800, 768,
                                              dtb, bc, 768, 0, b_dt_b, nullptr, nullptr);
    scanp_k<1><<<scan_blocks, 256, lds1, stream>>>(dtb, xc, bc, nullptr,
                                                   b_A_log, nullptr, nullptr, Aprod, Hend, nullptr);
    scan2_k<<<192, 256, 0, stream>>>(Aprod, Hend);
    scanp_k<3><<<scan_blocks, 256, lds3, stream>>>(dtb, xc, bc, xz,
                                                   b_A_log, b_Dp, Aprod, nullptr, nullptr, yb);
    gemm3_k<0,2,2><<<g_768, 256, 0, stream>>>(yb, DINNER, w_bout, 768, 768,
                                              fused, nullptr, 1536, 768, nullptr, nullptr, sidx);

    // ================= fusion MLP + residual =================
    gemm3_k<0,0,3><<<g_768, 256, 0, stream>>>(fused, 1536, w_1, 768, 1536,
                                              h1, nullptr, 768, 0, fuse_b1, nullptr, nullptr);
    gemm3_k<0,0,4><<<g_768, 256, 0, stream>>>(h1, DINNER, w_2, 768, 768,
                                              out, nullptr, 768, 0, fuse_b2, x, nullptr);
}

// Round 6
// 683.098 us; speedup vs baseline: 2.3419x; 1.0633x over previous
//
#include <hip/hip_runtime.h>
#include <hip/hip_bf16.h>
#include <cmath>

#define BB 4
#define LL 2304
#define CC 768
#define DSTATE 16
#define DINNER 768
#define DTRANK 48
#define MTOK (BB*LL)          // 9216
#define NCH 48
#define LCH (LL/NCH)          // 48

// per-direction strides (element units)
#define S_XZ   14155776L
#define S_XC   7077888L
#define S_DT   7077888L
#define S_BC   294912L
#define S_YB   7077888L
#define S_AP   2359296L

typedef __bf16 bf16_t;
typedef __bf16 bf16x8 __attribute__((ext_vector_type(8)));
typedef float  f32x4  __attribute__((ext_vector_type(4)));

__device__ __forceinline__ float silu_f(float v){ return v / (1.0f + __expf(-v)); }

typedef __attribute__((address_space(3))) void  lds_vt;
typedef __attribute__((address_space(1))) void  gbl_vt;
__device__ __forceinline__ void async_copy16(const void* g, void* l){
    __builtin_amdgcn_global_load_lds((const gbl_vt*)g, (lds_vt*)l, 16, 0, 0);
}

// ---------------- weight fp32 -> bf16 conversion ----------------------------
__global__ __launch_bounds__(256)
void wconv_k(const float* __restrict__ a0, const float* __restrict__ a1,
             const float* __restrict__ a2, const float* __restrict__ a3,
             const float* __restrict__ a4, const float* __restrict__ a5,
             const float* __restrict__ a6, const float* __restrict__ a7,
             bf16_t* __restrict__ dst)
{
    const int cum[9]  = {0,1179648,2359296,2949120,3538944,4718592,5308416,5332992,5357568};
    const int dofs[8] = {0,1179648,2359296,2949120,3538944,4718592,5898240,6512640};
    const float* srcs[8] = {a0,a1,a2,a3,a4,a5,a6,a7};
    int idx = blockIdx.x*256 + threadIdx.x;
    if (idx >= 5357568) return;
    int seg = 0;
    while (idx >= cum[seg+1]) ++seg;
    dst[dofs[seg] + idx - cum[seg]] = (bf16_t)srcs[seg][idx - cum[seg]];
}

// ---------------- combo weight: dst[n*768+k] = sum_r dtw[n*48+r]*xproj[r*768+k]
__global__ __launch_bounds__(256)
void combo_k(const float* __restrict__ dtw, const float* __restrict__ xproj,
             bf16_t* __restrict__ dst)
{
    __shared__ float row[48];
    int n = blockIdx.x;
    if (threadIdx.x < 48) row[threadIdx.x] = dtw[n*48 + threadIdx.x];
    __syncthreads();
#pragma unroll
    for (int kk=0; kk<3; ++kk){
        int k = threadIdx.x + 256*kk;
        float s = 0.f;
#pragma unroll 8
        for (int r=0; r<48; ++r) s += row[r]*xproj[r*768 + k];
        dst[n*768 + k] = (bf16_t)s;
    }
}

// ---------------- LayerNorm (per token, C=768) -> bf16 ----------------------
__global__ __launch_bounds__(256)
void ln_k(const float* __restrict__ x, const float* __restrict__ g,
          const float* __restrict__ bta, bf16_t* __restrict__ xn)
{
    int row = blockIdx.x;
    const float* xr = x + (long)row*CC;
    int tid = threadIdx.x;
    float v[3];
#pragma unroll
    for (int r=0;r<3;++r) v[r] = xr[tid + 256*r];
    float s  = v[0]+v[1]+v[2];
    float s2 = v[0]*v[0]+v[1]*v[1]+v[2]*v[2];
    __shared__ float red[8];
    for (int o=32;o;o>>=1){ s += __shfl_down(s,o); s2 += __shfl_down(s2,o); }
    int wv = tid>>6, ln = tid&63;
    if (ln==0){ red[wv]=s; red[4+wv]=s2; }
    __syncthreads();
    if (tid==0){
        red[0] = red[0]+red[1]+red[2]+red[3];
        red[4] = red[4]+red[5]+red[6]+red[7];
    }
    __syncthreads();
    float mu  = red[0]*(1.0f/CC);
    float var = red[4]*(1.0f/CC) - mu*mu;
    float rstd = rsqrtf(var + 1e-6f);
#pragma unroll
    for (int r=0;r<3;++r){
        int c = tid + 256*r;
        xn[(long)row*CC + c] = (bf16_t)((v[r]-mu)*rstd*g[c] + bta[c]);
    }
}

// ---------------- depthwise causal conv (k=4) + silu, both dirs -------------
__global__ __launch_bounds__(256)
void conv_k(const bf16_t* __restrict__ xz, const float* __restrict__ cw0,
            const float* __restrict__ cw1, const float* __restrict__ cb0,
            const float* __restrict__ cb1, bf16_t* __restrict__ xc)
{
    int dir = blockIdx.y;
    const bf16_t* xzd = xz + (long)dir*S_XZ;
    const float* cw = dir ? cw1 : cw0;
    const float* cb = dir ? cb1 : cb0;
    bf16_t* xcd = xc + (long)dir*S_XC;
    int idx = blockIdx.x*256 + threadIdx.x;
    if (idx >= MTOK*DINNER) return;
    int d = idx % DINNER; int row = idx / DINNER;
    int t = row % LL; int b4 = row - t;
    float acc = cb[d];
#pragma unroll
    for (int k=0;k<4;++k){
        int tt = t - 3 + k;
        if (tt >= 0) acc += cw[d*4 + k] * (float)xzd[(long)(b4 + tt)*1536 + d];
    }
    xcd[idx] = (bf16_t)silu_f(acc);
}

// ---------------- GEMM4: LDS-staged MFMA GEMM, 128x128 tile, BK=64 ----------
// Direction-fused: blockIdx.z = dir selects W / bias / gather sense / strides.
// Grid: x = m-tile (XCD locality), y = n-tile, z = dir.
// GATHER/SCATTER: 0 none, 3 runtime-dir (dir0: sidx[t], dir1: sidx[LL-1-t])
// EPI: 2 store bf16 (LDS-transposed wide stores) | 3 gelu+bias->bf16 (same) |
//      4 bias+resid->f32 scalar | 5 combo split (softplus->bf16, B/C->f32) scalar
template<int GATHER, int SCATTER, int EPI>
__global__ __launch_bounds__(256)
void gemm4_k(const bf16_t* __restrict__ A, long a_stride, int lda,
             const bf16_t* __restrict__ W0, const bf16_t* __restrict__ W1,
             int N, int K,
             void* __restrict__ out1, long o1_stride,
             void* __restrict__ out2, long o2_stride,
             int ldc, int ccol_stride,
             const float* __restrict__ bias0, const float* __restrict__ bias1,
             const float* __restrict__ resid,
             const int* __restrict__ sidx)
{
    __shared__ __align__(16) bf16_t smem[2*128*64];   // As | Bs ; reused as Cs
    bf16_t* As = smem;
    bf16_t* Bs = smem + 128*64;

    const int tid  = threadIdx.x;
    const int lane = tid & 63;
    const int w    = tid >> 6;
    const int ln16 = lane & 15;
    const int q    = lane >> 4;
    const int dir  = blockIdx.z;

    const bf16_t* Ad = A + (long)dir*a_stride;
    const bf16_t* W  = dir ? W1 : W0;
    const float* bias = dir ? bias1 : bias0;

    const int m0 = blockIdx.x*128;
    const int n0 = blockIdx.y*128;

    const int srow = lane >> 3;
    const int csrc = (lane & 7) ^ srow;
    const bf16_t* gA[4]; const bf16_t* gB[4];
#pragma unroll
    for (int inst=0; inst<4; ++inst){
        int row = w*32 + inst*8 + srow;
        int r = m0 + row;
        int sr = r;
        if (GATHER == 3){
            int t = r % LL; int bo = r - t;
            sr = bo + (dir ? sidx[LL-1-t] : sidx[t]);
        }
        gA[inst] = Ad + (long)sr*lda + csrc*8;
        int n = n0 + row; if (n >= N) n = N-1;
        gB[inst] = W + (long)n*K + csrc*8;
    }

    f32x4 acc[4][4];
#pragma unroll
    for (int i=0;i<4;++i)
#pragma unroll
      for (int j=0;j<4;++j) acc[i][j] = (f32x4){0.f,0.f,0.f,0.f};

    const int e = ln16 & 7;
    const int ar_base = ((w>>1)*64 + ln16)*64;
    const int br_base = ((w&1)*64 + ln16)*64;

    for (int k0 = 0; k0 < K; k0 += 64){
#pragma unroll
        for (int inst=0; inst<4; ++inst){
            bf16_t* la = As + (w*256 + inst*64)*8;
            bf16_t* lb = Bs + (w*256 + inst*64)*8;
            async_copy16(gA[inst] + k0, la);
            async_copy16(gB[inst] + k0, lb);
        }
        __syncthreads();
#pragma unroll
        for (int kk=0; kk<2; ++kk){
            const int ce = (((kk<<2)|q) ^ e)*8;
            bf16x8 af[4], bf[4];
#pragma unroll
            for (int i=0;i<4;++i) af[i] = *(const bf16x8*)&As[ar_base + i*16*64 + ce];
#pragma unroll
            for (int j=0;j<4;++j) bf[j] = *(const bf16x8*)&Bs[br_base + j*16*64 + ce];
#pragma unroll
            for (int i=0;i<4;++i)
#pragma unroll
              for (int j=0;j<4;++j)
                acc[i][j] = __builtin_amdgcn_mfma_f32_16x16x32_bf16(af[i], bf[j], acc[i][j], 0,0,0);
        }
        __syncthreads();
    }

    const int mw = (w>>1)*64;
    const int nw = (w&1)*64;
    const int ccolb = ccol_stride*dir;

    if (EPI==2 || EPI==3){
        // ---- LDS-transposed epilogue: stage C tile (128x128 bf16 = 32KB) ----
        bf16_t* Cs = smem;
#pragma unroll
        for (int i=0;i<4;++i){
#pragma unroll
            for (int reg=0; reg<4; ++reg){
                int rowl = mw + i*16 + q*4 + reg;
#pragma unroll
                for (int j=0;j<4;++j){
                    int coll = nw + j*16 + ln16;
                    float v = acc[i][j][reg];
                    if (EPI==3){
                        v += bias[n0 + coll];
                        v = 0.5f*v*(1.0f + erff(v*0.70710678118654752f));
                    }
                    Cs[rowl*128 + coll] = (bf16_t)v;
                }
            }
        }
        __syncthreads();
        bf16_t* o = (bf16_t*)out1 + (long)dir*o1_stride;
#pragma unroll
        for (int c=0;c<8;++c){
            int chunk = tid + 256*c;            // 0..2047
            int rowl = chunk >> 4;
            int coll = (chunk & 15)*8;
            int r = m0 + rowl;
            int orow = r;
            if (SCATTER == 3){
                int t = r % LL; int bo = r - t;
                orow = bo + (dir ? sidx[LL-1-t] : sidx[t]);
            }
            *(int4*)&o[(long)orow*ldc + ccolb + n0 + coll] = *(const int4*)&Cs[rowl*128 + coll];
        }
    } else {
        // ---- scalar epilogue (EPI 4/5) ----
#pragma unroll
        for (int i=0;i<4;++i){
#pragma unroll
            for (int reg=0; reg<4; ++reg){
                int r = m0 + mw + i*16 + q*4 + reg;
#pragma unroll
                for (int j=0;j<4;++j){
                    int col = n0 + nw + j*16 + ln16;
                    if (col >= N) continue;
                    float v = acc[i][j][reg];
                    if (EPI==4){
                        v += bias[col] + resid[(long)r*CC + col];
                        ((float*)out1)[(long)r*ldc + col] = v;
                    } else { // EPI==5
                        if (col < 768){
                            v += bias[col];
                            v = fmaxf(v,0.f) + log1pf(__expf(-fabsf(v)));
                            ((bf16_t*)out1 + (long)dir*o1_stride)[(long)r*768 + col] = (bf16_t)v;
                        } else {
                            ((float*)out2 + (long)dir*o2_stride)[(long)r*32 + (col-768)] = v;
                        }
                    }
                }
            }
        }
    }
}

// ---------------- LDS-staged chunked selective scan (dir-fused) -------------
// Grid: (BB*NCH*12, 2). Block tile = 64 d x 48 t.
// LDS: [dt bf16 | xc bf16 | bc f32 | z bf16 | y bf16], each 6144 B.
template<int PASS>
__global__ __launch_bounds__(256)
void scanp_k(const bf16_t* __restrict__ dtp, const bf16_t* __restrict__ xcp,
             const float* __restrict__ bcp, const bf16_t* __restrict__ xzp,
             const float* __restrict__ Al0, const float* __restrict__ Al1,
             const float* __restrict__ Dp0, const float* __restrict__ Dp1,
             float* __restrict__ Aprod, float* __restrict__ Hend,
             bf16_t* __restrict__ yout)
{
    extern __shared__ __align__(16) char smem[];
    bf16_t* s_dt = (bf16_t*)smem;            // 6144 B
    bf16_t* s_xc = (bf16_t*)(smem + 6144);   // 6144 B
    float*  s_bc = (float*) (smem + 12288);  // 6144 B
    bf16_t* s_z  = (bf16_t*)(smem + 18432);  // 6144 B (PASS 3)
    bf16_t* s_y  = (bf16_t*)(smem + 24576);  // 6144 B (PASS 3)

    int dir = blockIdx.y;
    int blk = blockIdx.x;
    int dblk = blk % 12; int tmp = blk / 12;
    int j = tmp % NCH; int b = tmp / NCH;
    int tid = threadIdx.x;
    long tbase = (long)b*LL + (long)j*LCH;

    const bf16_t* gdt = dtp + dir*S_DT + tbase*DINNER + dblk*64;
    const bf16_t* gxc = xcp + dir*S_XC + tbase*DINNER + dblk*64;
    const float*  gbc = bcp + dir*S_BC + tbase*32;
    {
        int c = tid, t = c>>3, dc = c&7;
        async_copy16(gdt + (long)t*DINNER + dc*8, s_dt + c*8);
        async_copy16(gxc + (long)t*DINNER + dc*8, s_xc + c*8);
        async_copy16(gbc + (long)t*32 + dc*4, s_bc + c*4);
        if (tid < 128){
            c = tid + 256; t = c>>3; dc = c&7;
            async_copy16(gdt + (long)t*DINNER + dc*8, s_dt + c*8);
            async_copy16(gxc + (long)t*DINNER + dc*8, s_xc + c*8);
            async_copy16(gbc + (long)t*32 + dc*4, s_bc + c*4);
        }
    }
    if (PASS==3){
        const bf16_t* gz = xzp + dir*S_XZ + tbase*1536 + DINNER + dblk*64;
        int c = tid, t = c>>3, dc = c&7;
        async_copy16(gz + (long)t*1536 + dc*8, s_z + c*8);
        if (tid < 128){ c = tid+256; t = c>>3; dc = c&7;
            async_copy16(gz + (long)t*1536 + dc*8, s_z + c*8); }
    }
    __syncthreads();

    int lane = tid & 63, w = tid >> 6;
    int d_low = lane & 15, sg = lane >> 4;
    int dl = w*16 + d_low;
    int d  = dblk*64 + dl;

    const float* Al = dir ? Al1 : Al0;
    f32x4 al = *(const f32x4*)&Al[d*DSTATE + sg*4];
    float a_c[4];
#pragma unroll
    for (int k=0;k<4;++k) a_c[k] = -__expf(al[k]);

    float h[4] = {0.f,0.f,0.f,0.f};
    float dpv = 0.f;
    long o = dir*S_AP + ((long)(b*NCH + j)*DINNER + d)*DSTATE + sg*4;
    if (PASS==3){
        f32x4 hin = *(const f32x4*)&Aprod[o];   // carries written in place
#pragma unroll
        for (int k=0;k<4;++k) h[k] = hin[k];
        dpv = (dir ? Dp1 : Dp0)[d];
    }
    float sdt = 0.f;

    for (int t=0; t<LCH; ++t){
        float dt = (float)s_dt[t*64 + dl];
        float xv = (float)s_xc[t*64 + dl];
        f32x4 Bv = *(const f32x4*)&s_bc[t*32 + sg*4];
        float c = dt*xv;
        if (PASS==1) sdt += dt;
#pragma unroll
        for (int k=0;k<4;++k){
            float da = __expf(dt * a_c[k]);
            h[k] = da*h[k] + c*Bv[k];
        }
        if (PASS==3){
            f32x4 Cv = *(const f32x4*)&s_bc[t*32 + 16 + sg*4];
            float p = h[0]*Cv[0] + h[1]*Cv[1] + h[2]*Cv[2] + h[3]*Cv[3];
            p += __shfl_xor(p, 16);
            p += __shfl_xor(p, 32);
            if (sg == 0){
                float z = (float)s_z[t*64 + dl];
                s_y[t*64 + dl] = (bf16_t)((p + dpv*xv) * silu_f(z));
            }
        }
    }

    if (PASS==1){
        f32x4 ap, hv;
#pragma unroll
        for (int k=0;k<4;++k){ ap[k] = __expf(sdt * a_c[k]); hv[k] = h[k]; }
        *(f32x4*)&Aprod[o] = ap;
        *(f32x4*)&Hend[o]  = hv;
    }
    if (PASS==3){
        __syncthreads();
        bf16_t* gy = yout + dir*S_YB + tbase*DINNER + dblk*64;
        int c = tid, t = c>>3, dc = c&7;
        *(int4*)(gy + (long)t*DINNER + dc*8) = *(const int4*)&s_y[c*8];
        if (tid < 128){ c = tid+256; t = c>>3; dc = c&7;
            *(int4*)(gy + (long)t*DINNER + dc*8) = *(const int4*)&s_y[c*8]; }
    }
}

// pass2: sequential combine (both dirs); carry-in written IN PLACE into Aprod
__global__ __launch_bounds__(256)
void scan2_k(float* __restrict__ Aprod, const float* __restrict__ Hend)
{
    int idx = blockIdx.x*256 + threadIdx.x;
    if (idx >= 2*BB*DINNER*DSTATE) return;
    int dir = idx / (BB*DINNER*DSTATE);
    int rem = idx - dir*(BB*DINNER*DSTATE);
    int b = rem / (DINNER*DSTATE);
    int ds = rem % (DINNER*DSTATE);
    long base = (long)dir*S_AP;
    float h = 0.f;
    for (int j=0;j<NCH;++j){
        long o = base + (long)(b*NCH+j)*DINNER*DSTATE + ds;
        float ap = Aprod[o];
        float he = Hend[o];
        Aprod[o] = h;
        h = ap*h + he;
    }
}

// ----------------------------------------------------------------------------
extern "C" void kernel_launch(void* const* d_in, const int* in_sizes, int n_in,
                              void* d_out, int out_size, void* d_ws, size_t ws_size,
                              hipStream_t stream)
{
    const float* x       = (const float*)d_in[0];
    const int*   sidx    = (const int*)  d_in[1];
    const float* norm_g  = (const float*)d_in[2];
    const float* norm_b  = (const float*)d_in[3];
    const float* fuse_w1 = (const float*)d_in[4];
    const float* fuse_b1 = (const float*)d_in[5];
    const float* fuse_w2 = (const float*)d_in[6];
    const float* fuse_b2 = (const float*)d_in[7];
    const float* f_in_w   = (const float*)d_in[8];
    const float* f_conv_w = (const float*)d_in[9];
    const float* f_conv_b = (const float*)d_in[10];
    const float* f_xproj  = (const float*)d_in[11];
    const float* f_dt_w   = (const float*)d_in[12];
    const float* f_dt_b   = (const float*)d_in[13];
    const float* f_A_log  = (const float*)d_in[14];
    const float* f_Dp     = (const float*)d_in[15];
    const float* f_out_w  = (const float*)d_in[16];
    const float* b_in_w   = (const float*)d_in[17];
    const float* b_conv_w = (const float*)d_in[18];
    const float* b_conv_b = (const float*)d_in[19];
    const float* b_xproj  = (const float*)d_in[20];
    const float* b_dt_w   = (const float*)d_in[21];
    const float* b_dt_b   = (const float*)d_in[22];
    const float* b_A_log  = (const float*)d_in[23];
    const float* b_Dp     = (const float*)d_in[24];
    const float* b_out_w  = (const float*)d_in[25];
    float* out = (float*)d_out;

    // ---- workspace layout (float units) — total 59,301,888 fl = 237.2 MB ----
    float* ws    = (float*)d_ws;
    bf16_t* xn   = (bf16_t*)ws;                        // 7,077,888 bf16
    bf16_t* xz   = (bf16_t*)(ws + 3538944);            // 2 x 14,155,776 bf16
    bf16_t* xc   = (bf16_t*)(ws + 17694720);           // 2 x 7,077,888 bf16
    bf16_t* dtb  = (bf16_t*)(ws + 24772608);           // 2 x 7,077,888 bf16
    float* bc    = ws + 31850496;                      // 2 x 294,912 fl
    bf16_t* yb   = (bf16_t*)(ws + 32440320);           // 2 x 7,077,888 bf16
    bf16_t* fused= (bf16_t*)(ws + 39518208);           // 14,155,776 bf16
    float* Aprod = ws + 46596096;                      // 2 x 2,359,296 fl
    float* Hend  = ws + 51314688;                      // 2 x 2,359,296 fl
    bf16_t* wbf  = (bf16_t*)(ws + 56033280);           // 6,537,216 bf16
    bf16_t* h1 = yb;

    bf16_t* w_fin    = wbf + 0;
    bf16_t* w_bin    = wbf + 1179648;
    bf16_t* w_fout   = wbf + 2359296;
    bf16_t* w_bout   = wbf + 2949120;
    bf16_t* w_1      = wbf + 3538944;
    bf16_t* w_2      = wbf + 4718592;
    bf16_t* w_fcombo = wbf + 5308416;   // 800 x 768
    bf16_t* w_bcombo = wbf + 5922816;   // 800 x 768

    wconv_k<<<20928, 256, 0, stream>>>(f_in_w, b_in_w, f_out_w, b_out_w,
                                       fuse_w1, fuse_w2,
                                       f_xproj + 48*768, b_xproj + 48*768, wbf);
    combo_k<<<768, 256, 0, stream>>>(f_dt_w, f_xproj, w_fcombo);
    combo_k<<<768, 256, 0, stream>>>(b_dt_w, b_xproj, w_bcombo);
    ln_k<<<MTOK, 256, 0, stream>>>(x, norm_g, norm_b, xn);

    const unsigned lds1 = 18432, lds3 = 30720;

    // ---- in-projection (both dirs) ----
    gemm4_k<3,0,2><<<dim3(72,12,2), 256, 0, stream>>>(
        xn, 0, CC, w_fin, w_bin, 1536, 768,
        xz, S_XZ, nullptr, 0, 1536, 0, nullptr, nullptr, nullptr, sidx);
    // ---- depthwise conv (both dirs) ----
    conv_k<<<dim3(27648,2), 256, 0, stream>>>(xz, f_conv_w, b_conv_w,
                                              f_conv_b, b_conv_b, xc);
    // ---- combo projection: softplus(dt) + B/C (both dirs) ----
    gemm4_k<0,0,5><<<dim3(72,7,2), 256, 0, stream>>>(
        xc, S_XC, DINNER, w_fcombo, w_bcombo, 800, 768,
        dtb, S_DT, bc, S_BC, 768, 0, f_dt_b, b_dt_b, nullptr, nullptr);
    // ---- selective scan (both dirs) ----
    scanp_k<1><<<dim3(BB*NCH*12,2), 256, lds1, stream>>>(
        dtb, xc, bc, nullptr, f_A_log, b_A_log, f_Dp, b_Dp, Aprod, Hend, nullptr);
    scan2_k<<<384, 256, 0, stream>>>(Aprod, Hend);
    scanp_k<3><<<dim3(BB*NCH*12,2), 256, lds3, stream>>>(
        dtb, xc, bc, xz, f_A_log, b_A_log, f_Dp, b_Dp, Aprod, Hend, yb);
    // ---- out-projection -> fused[:, dir*768 ..] (both dirs) ----
    gemm4_k<0,3,2><<<dim3(72,6,2), 256, 0, stream>>>(
        yb, S_YB, DINNER, w_fout, w_bout, 768, 768,
        fused, 0, nullptr, 0, 1536, 768, nullptr, nullptr, nullptr, sidx);
    // ---- fusion MLP + residual ----
    gemm4_k<0,0,3><<<dim3(72,6,1), 256, 0, stream>>>(
        fused, 0, 1536, w_1, w_1, 768, 1536,
        h1, 0, nullptr, 0, 768, 0, fuse_b1, fuse_b1, nullptr, nullptr);
    gemm4_k<0,0,4><<<dim3(72,6,1), 256, 0, stream>>>(
        h1, 0, DINNER, w_2, w_2, 768, 768,
        out, 0, nullptr, 0, 768, 0, fuse_b2, fuse_b2, x, nullptr);
}

// Round 7
// 632.350 us; speedup vs baseline: 2.5298x; 1.0803x over previous
//
#include <hip/hip_runtime.h>
#include <hip/hip_bf16.h>
#include <cmath>

#define BB 4
#define LL 2304
#define CC 768
#define DSTATE 16
#define DINNER 768
#define DTRANK 48
#define MTOK (BB*LL)          // 9216
#define NCH 48
#define LCH (LL/NCH)          // 48

// per-direction strides (element units)
#define S_XZ   14155776L
#define S_XC   7077888L
#define S_DT   7077888L
#define S_BC   294912L
#define S_YB   7077888L
#define S_AP   2359296L

typedef __bf16 bf16_t;
typedef __bf16 bf16x8 __attribute__((ext_vector_type(8)));
typedef float  f32x4  __attribute__((ext_vector_type(4)));

__device__ __forceinline__ float silu_f(float v){ return v / (1.0f + __expf(-v)); }

typedef __attribute__((address_space(3))) void  lds_vt;
typedef __attribute__((address_space(1))) void  gbl_vt;
__device__ __forceinline__ void async_copy16(const void* g, void* l){
    __builtin_amdgcn_global_load_lds((const gbl_vt*)g, (lds_vt*)l, 16, 0, 0);
}

// ---------------- weight fp32 -> bf16 conversion ----------------------------
// segments: f_in, b_in, fuse_w1, fuse_w2, f_bc(xproj rows 48..79), b_bc
__global__ __launch_bounds__(256)
void wconv_k(const float* __restrict__ a0, const float* __restrict__ a1,
             const float* __restrict__ a2, const float* __restrict__ a3,
             const float* __restrict__ a4, const float* __restrict__ a5,
             bf16_t* __restrict__ dst)
{
    const int cum[7]  = {0,1179648,2359296,3538944,4128768,4153344,4177920};
    const int dofs[6] = {0,1179648,2359296,3538944,4718592,5332992};
    const float* srcs[6] = {a0,a1,a2,a3,a4,a5};
    int idx = blockIdx.x*256 + threadIdx.x;
    if (idx >= 4177920) return;
    int seg = 0;
    while (idx >= cum[seg+1]) ++seg;
    dst[dofs[seg] + idx - cum[seg]] = (bf16_t)srcs[seg][idx - cum[seg]];
}

// ---------------- transpose+convert 768x768 fp32 -> bf16 (dst = src^T) ------
__global__ __launch_bounds__(256)
void transp_k(const float* __restrict__ s0, const float* __restrict__ s1,
              bf16_t* __restrict__ d0, bf16_t* __restrict__ d1)
{
    __shared__ float tile[32][33];
    const float* src = blockIdx.z ? s1 : s0;
    bf16_t* dst = blockIdx.z ? d1 : d0;
    int c0 = blockIdx.y*32, d0c = blockIdx.x*32;
    int tx = threadIdx.x & 31, ty = threadIdx.x >> 5;   // ty 0..7
#pragma unroll
    for (int r=0;r<4;++r)
        tile[ty+8*r][tx] = src[(long)(c0+ty+8*r)*768 + d0c+tx];
    __syncthreads();
#pragma unroll
    for (int r=0;r<4;++r)
        dst[(long)(d0c+ty+8*r)*768 + c0+tx] = (bf16_t)tile[tx][ty+8*r];
}

// ---------------- inverse permutations ---------------------------------------
// rev_f[sidx[t]] = t ; rev_b[sidx[LL-1-t]] = t
__global__ __launch_bounds__(256)
void inv_k(const int* __restrict__ sidx, int* __restrict__ rf, int* __restrict__ rb)
{
    int t = blockIdx.x*256 + threadIdx.x;
    if (t >= LL) return;
    rf[sidx[t]] = t;
    rb[sidx[LL-1-t]] = t;
}

// ---------------- combo weight: dst[n*768+k] = sum_r dtw[n*48+r]*xproj[r*768+k]
__global__ __launch_bounds__(256)
void combo_k(const float* __restrict__ dtw, const float* __restrict__ xproj,
             bf16_t* __restrict__ dst)
{
    __shared__ float row[48];
    int n = blockIdx.x;
    if (threadIdx.x < 48) row[threadIdx.x] = dtw[n*48 + threadIdx.x];
    __syncthreads();
#pragma unroll
    for (int kk=0; kk<3; ++kk){
        int k = threadIdx.x + 256*kk;
        float s = 0.f;
#pragma unroll 8
        for (int r=0; r<48; ++r) s += row[r]*xproj[r*768 + k];
        dst[n*768 + k] = (bf16_t)s;
    }
}

// ---------------- LayerNorm (per token, C=768) -> bf16 ----------------------
__global__ __launch_bounds__(256)
void ln_k(const float* __restrict__ x, const float* __restrict__ g,
          const float* __restrict__ bta, bf16_t* __restrict__ xn)
{
    int row = blockIdx.x;
    const float* xr = x + (long)row*CC;
    int tid = threadIdx.x;
    float v[3];
#pragma unroll
    for (int r=0;r<3;++r) v[r] = xr[tid + 256*r];
    float s  = v[0]+v[1]+v[2];
    float s2 = v[0]*v[0]+v[1]*v[1]+v[2]*v[2];
    __shared__ float red[8];
    for (int o=32;o;o>>=1){ s += __shfl_down(s,o); s2 += __shfl_down(s2,o); }
    int wv = tid>>6, ln = tid&63;
    if (ln==0){ red[wv]=s; red[4+wv]=s2; }
    __syncthreads();
    if (tid==0){
        red[0] = red[0]+red[1]+red[2]+red[3];
        red[4] = red[4]+red[5]+red[6]+red[7];
    }
    __syncthreads();
    float mu  = red[0]*(1.0f/CC);
    float var = red[4]*(1.0f/CC) - mu*mu;
    float rstd = rsqrtf(var + 1e-6f);
#pragma unroll
    for (int r=0;r<3;++r){
        int c = tid + 256*r;
        xn[(long)row*CC + c] = (bf16_t)((v[r]-mu)*rstd*g[c] + bta[c]);
    }
}

// ---------------- depthwise causal conv (k=4) + silu, both dirs -------------
__global__ __launch_bounds__(256)
void conv_k(const bf16_t* __restrict__ xz, const float* __restrict__ cw0,
            const float* __restrict__ cw1, const float* __restrict__ cb0,
            const float* __restrict__ cb1, bf16_t* __restrict__ xc)
{
    int dir = blockIdx.y;
    const bf16_t* xzd = xz + (long)dir*S_XZ;
    const float* cw = dir ? cw1 : cw0;
    const float* cb = dir ? cb1 : cb0;
    bf16_t* xcd = xc + (long)dir*S_XC;
    int idx = blockIdx.x*256 + threadIdx.x;
    if (idx >= MTOK*DINNER) return;
    int d = idx % DINNER; int row = idx / DINNER;
    int t = row % LL; int b4 = row - t;
    float acc = cb[d];
#pragma unroll
    for (int k=0;k<4;++k){
        int tt = t - 3 + k;
        if (tt >= 0) acc += cw[d*4 + k] * (float)xzd[(long)(b4 + tt)*1536 + d];
    }
    xcd[idx] = (bf16_t)silu_f(acc);
}

// ---------------- GEMM4: LDS-staged MFMA GEMM, 128x128 tile, BK=64 ----------
// Grid: x = m-tile (XCD locality), y = n-tile, z = dir.
// GATHER: 0 none, 3 runtime-dir (dir0: sidx[t], dir1: sidx[LL-1-t]),
//         4 dual-phase A (k<768: A row bo+ridx0[t]; k>=768: A+a_stride row bo+ridx1[t])
// SCATTER: 0 none, 3 runtime-dir
// EPI: 2 store bf16 (LDS-transposed wide stores) | 3 gelu+bias->bf16 (same) |
//      4 bias+resid->f32 scalar | 5 combo split (softplus->bf16, B/C->f32) scalar
template<int GATHER, int SCATTER, int EPI>
__global__ __launch_bounds__(256)
void gemm4_k(const bf16_t* __restrict__ A, long a_stride, int lda,
             const bf16_t* __restrict__ W0, const bf16_t* __restrict__ W1,
             int N, int K,
             void* __restrict__ out1, long o1_stride,
             void* __restrict__ out2, long o2_stride,
             int ldc, int ccol_stride,
             const float* __restrict__ bias0, const float* __restrict__ bias1,
             const float* __restrict__ resid,
             const int* __restrict__ sidx,
             const int* __restrict__ ridx0, const int* __restrict__ ridx1)
{
    __shared__ __align__(16) bf16_t smem[2*128*64];   // As | Bs ; reused as Cs
    bf16_t* As = smem;
    bf16_t* Bs = smem + 128*64;

    const int tid  = threadIdx.x;
    const int lane = tid & 63;
    const int w    = tid >> 6;
    const int ln16 = lane & 15;
    const int q    = lane >> 4;
    const int dir  = blockIdx.z;

    const bf16_t* Ad = A + (long)dir*a_stride;
    const bf16_t* W  = dir ? W1 : W0;
    const float* bias = dir ? bias1 : bias0;

    const int m0 = blockIdx.x*128;
    const int n0 = blockIdx.y*128;

    const int srow = lane >> 3;
    const int csrc = (lane & 7) ^ srow;
    const bf16_t* gA[4]; const bf16_t* gA1[4]; const bf16_t* gB[4];
#pragma unroll
    for (int inst=0; inst<4; ++inst){
        int row = w*32 + inst*8 + srow;
        int r = m0 + row;
        if (GATHER == 4){
            int t = r % LL; int bo = r - t;
            gA[inst]  = A + (long)(bo + ridx0[t])*lda + csrc*8;
            gA1[inst] = A + a_stride + (long)(bo + ridx1[t])*lda + csrc*8;
        } else {
            int sr = r;
            if (GATHER == 3){
                int t = r % LL; int bo = r - t;
                sr = bo + (dir ? sidx[LL-1-t] : sidx[t]);
            }
            gA[inst] = Ad + (long)sr*lda + csrc*8;
        }
        int n = n0 + row; if (n >= N) n = N-1;
        gB[inst] = W + (long)n*K + csrc*8;
    }

    f32x4 acc[4][4];
#pragma unroll
    for (int i=0;i<4;++i)
#pragma unroll
      for (int j=0;j<4;++j) acc[i][j] = (f32x4){0.f,0.f,0.f,0.f};

    const int e = ln16 & 7;
    const int ar_base = ((w>>1)*64 + ln16)*64;
    const int br_base = ((w&1)*64 + ln16)*64;

    for (int k0 = 0; k0 < K; k0 += 64){
#pragma unroll
        for (int inst=0; inst<4; ++inst){
            bf16_t* la = As + (w*256 + inst*64)*8;
            bf16_t* lb = Bs + (w*256 + inst*64)*8;
            const bf16_t* asrc;
            if (GATHER == 4)
                asrc = (k0 >= 768) ? (gA1[inst] + (k0 - 768)) : (gA[inst] + k0);
            else
                asrc = gA[inst] + k0;
            async_copy16(asrc, la);
            async_copy16(gB[inst] + k0, lb);
        }
        __syncthreads();
#pragma unroll
        for (int kk=0; kk<2; ++kk){
            const int ce = (((kk<<2)|q) ^ e)*8;
            bf16x8 af[4], bf[4];
#pragma unroll
            for (int i=0;i<4;++i) af[i] = *(const bf16x8*)&As[ar_base + i*16*64 + ce];
#pragma unroll
            for (int j=0;j<4;++j) bf[j] = *(const bf16x8*)&Bs[br_base + j*16*64 + ce];
#pragma unroll
            for (int i=0;i<4;++i)
#pragma unroll
              for (int j=0;j<4;++j)
                acc[i][j] = __builtin_amdgcn_mfma_f32_16x16x32_bf16(af[i], bf[j], acc[i][j], 0,0,0);
        }
        __syncthreads();
    }

    const int mw = (w>>1)*64;
    const int nw = (w&1)*64;
    const int ccolb = ccol_stride*dir;

    if (EPI==2 || EPI==3){
        // ---- LDS-transposed epilogue: stage C tile (128x128 bf16 = 32KB) ----
        bf16_t* Cs = smem;
#pragma unroll
        for (int i=0;i<4;++i){
#pragma unroll
            for (int reg=0; reg<4; ++reg){
                int rowl = mw + i*16 + q*4 + reg;
#pragma unroll
                for (int j=0;j<4;++j){
                    int coll = nw + j*16 + ln16;
                    float v = acc[i][j][reg];
                    if (EPI==3){
                        v += bias[n0 + coll];
                        v = 0.5f*v*(1.0f + erff(v*0.70710678118654752f));
                    }
                    Cs[rowl*128 + coll] = (bf16_t)v;
                }
            }
        }
        __syncthreads();
        bf16_t* o = (bf16_t*)out1 + (long)dir*o1_stride;
#pragma unroll
        for (int c=0;c<8;++c){
            int chunk = tid + 256*c;            // 0..2047
            int rowl = chunk >> 4;
            int coll = (chunk & 15)*8;
            int r = m0 + rowl;
            int orow = r;
            if (SCATTER == 3){
                int t = r % LL; int bo = r - t;
                orow = bo + (dir ? sidx[LL-1-t] : sidx[t]);
            }
            *(int4*)&o[(long)orow*ldc + ccolb + n0 + coll] = *(const int4*)&Cs[rowl*128 + coll];
        }
    } else {
        // ---- scalar epilogue (EPI 4/5) ----
#pragma unroll
        for (int i=0;i<4;++i){
#pragma unroll
            for (int reg=0; reg<4; ++reg){
                int r = m0 + mw + i*16 + q*4 + reg;
#pragma unroll
                for (int j=0;j<4;++j){
                    int col = n0 + nw + j*16 + ln16;
                    if (col >= N) continue;
                    float v = acc[i][j][reg];
                    if (EPI==4){
                        v += bias[col] + resid[(long)r*CC + col];
                        ((float*)out1)[(long)r*ldc + col] = v;
                    } else { // EPI==5
                        if (col < 768){
                            v += bias[col];
                            v = fmaxf(v,0.f) + log1pf(__expf(-fabsf(v)));
                            ((bf16_t*)out1 + (long)dir*o1_stride)[(long)r*768 + col] = (bf16_t)v;
                        } else {
                            ((float*)out2 + (long)dir*o2_stride)[(long)r*32 + (col-768)] = v;
                        }
                    }
                }
            }
        }
    }
}

// ---------------- LDS-staged chunked selective scan (dir-fused) -------------
template<int PASS>
__global__ __launch_bounds__(256)
void scanp_k(const bf16_t* __restrict__ dtp, const bf16_t* __restrict__ xcp,
             const float* __restrict__ bcp, const bf16_t* __restrict__ xzp,
             const float* __restrict__ Al0, const float* __restrict__ Al1,
             const float* __restrict__ Dp0, const float* __restrict__ Dp1,
             float* __restrict__ Aprod, float* __restrict__ Hend,
             bf16_t* __restrict__ yout)
{
    extern __shared__ __align__(16) char smem[];
    bf16_t* s_dt = (bf16_t*)smem;            // 6144 B
    bf16_t* s_xc = (bf16_t*)(smem + 6144);   // 6144 B
    float*  s_bc = (float*) (smem + 12288);  // 6144 B
    bf16_t* s_z  = (bf16_t*)(smem + 18432);  // 6144 B (PASS 3)
    bf16_t* s_y  = (bf16_t*)(smem + 24576);  // 6144 B (PASS 3)

    int dir = blockIdx.y;
    int blk = blockIdx.x;
    int dblk = blk % 12; int tmp = blk / 12;
    int j = tmp % NCH; int b = tmp / NCH;
    int tid = threadIdx.x;
    long tbase = (long)b*LL + (long)j*LCH;

    const bf16_t* gdt = dtp + dir*S_DT + tbase*DINNER + dblk*64;
    const bf16_t* gxc = xcp + dir*S_XC + tbase*DINNER + dblk*64;
    const float*  gbc = bcp + dir*S_BC + tbase*32;
    {
        int c = tid, t = c>>3, dc = c&7;
        async_copy16(gdt + (long)t*DINNER + dc*8, s_dt + c*8);
        async_copy16(gxc + (long)t*DINNER + dc*8, s_xc + c*8);
        async_copy16(gbc + (long)t*32 + dc*4, s_bc + c*4);
        if (tid < 128){
            c = tid + 256; t = c>>3; dc = c&7;
            async_copy16(gdt + (long)t*DINNER + dc*8, s_dt + c*8);
            async_copy16(gxc + (long)t*DINNER + dc*8, s_xc + c*8);
            async_copy16(gbc + (long)t*32 + dc*4, s_bc + c*4);
        }
    }
    if (PASS==3){
        const bf16_t* gz = xzp + dir*S_XZ + tbase*1536 + DINNER + dblk*64;
        int c = tid, t = c>>3, dc = c&7;
        async_copy16(gz + (long)t*1536 + dc*8, s_z + c*8);
        if (tid < 128){ c = tid+256; t = c>>3; dc = c&7;
            async_copy16(gz + (long)t*1536 + dc*8, s_z + c*8); }
    }
    __syncthreads();

    int lane = tid & 63, w = tid >> 6;
    int d_low = lane & 15, sg = lane >> 4;
    int dl = w*16 + d_low;
    int d  = dblk*64 + dl;

    const float* Al = dir ? Al1 : Al0;
    f32x4 al = *(const f32x4*)&Al[d*DSTATE + sg*4];
    float a_c[4];
#pragma unroll
    for (int k=0;k<4;++k) a_c[k] = -__expf(al[k]);

    float h[4] = {0.f,0.f,0.f,0.f};
    float dpv = 0.f;
    long o = dir*S_AP + ((long)(b*NCH + j)*DINNER + d)*DSTATE + sg*4;
    if (PASS==3){
        f32x4 hin = *(const f32x4*)&Aprod[o];   // carries written in place
#pragma unroll
        for (int k=0;k<4;++k) h[k] = hin[k];
        dpv = (dir ? Dp1 : Dp0)[d];
    }
    float sdt = 0.f;

    for (int t=0; t<LCH; ++t){
        float dt = (float)s_dt[t*64 + dl];
        float xv = (float)s_xc[t*64 + dl];
        f32x4 Bv = *(const f32x4*)&s_bc[t*32 + sg*4];
        float c = dt*xv;
        if (PASS==1) sdt += dt;
#pragma unroll
        for (int k=0;k<4;++k){
            float da = __expf(dt * a_c[k]);
            h[k] = da*h[k] + c*Bv[k];
        }
        if (PASS==3){
            f32x4 Cv = *(const f32x4*)&s_bc[t*32 + 16 + sg*4];
            float p = h[0]*Cv[0] + h[1]*Cv[1] + h[2]*Cv[2] + h[3]*Cv[3];
            p += __shfl_xor(p, 16);
            p += __shfl_xor(p, 32);
            if (sg == 0){
                float z = (float)s_z[t*64 + dl];
                s_y[t*64 + dl] = (bf16_t)((p + dpv*xv) * silu_f(z));
            }
        }
    }

    if (PASS==1){
        f32x4 ap, hv;
#pragma unroll
        for (int k=0;k<4;++k){ ap[k] = __expf(sdt * a_c[k]); hv[k] = h[k]; }
        *(f32x4*)&Aprod[o] = ap;
        *(f32x4*)&Hend[o]  = hv;
    }
    if (PASS==3){
        __syncthreads();
        bf16_t* gy = yout + dir*S_YB + tbase*DINNER + dblk*64;
        int c = tid, t = c>>3, dc = c&7;
        *(int4*)(gy + (long)t*DINNER + dc*8) = *(const int4*)&s_y[c*8];
        if (tid < 128){ c = tid+256; t = c>>3; dc = c&7;
            *(int4*)(gy + (long)t*DINNER + dc*8) = *(const int4*)&s_y[c*8]; }
    }
}

// pass2: sequential combine (both dirs); carry-in written IN PLACE into Aprod
__global__ __launch_bounds__(256)
void scan2_k(float* __restrict__ Aprod, const float* __restrict__ Hend)
{
    int idx = blockIdx.x*256 + threadIdx.x;
    if (idx >= 2*BB*DINNER*DSTATE) return;
    int dir = idx / (BB*DINNER*DSTATE);
    int rem = idx - dir*(BB*DINNER*DSTATE);
    int b = rem / (DINNER*DSTATE);
    int ds = rem % (DINNER*DSTATE);
    long base = (long)dir*S_AP;
    float h = 0.f;
    for (int j=0;j<NCH;++j){
        long o = base + (long)(b*NCH+j)*DINNER*DSTATE + ds;
        float ap = Aprod[o];
        float he = Hend[o];
        Aprod[o] = h;
        h = ap*h + he;
    }
}

// ----------------------------------------------------------------------------
extern "C" void kernel_launch(void* const* d_in, const int* in_sizes, int n_in,
                              void* d_out, int out_size, void* d_ws, size_t ws_size,
                              hipStream_t stream)
{
    const float* x       = (const float*)d_in[0];
    const int*   sidx    = (const int*)  d_in[1];
    const float* norm_g  = (const float*)d_in[2];
    const float* norm_b  = (const float*)d_in[3];
    const float* fuse_w1 = (const float*)d_in[4];
    const float* fuse_b1 = (const float*)d_in[5];
    const float* fuse_w2 = (const float*)d_in[6];
    const float* fuse_b2 = (const float*)d_in[7];
    const float* f_in_w   = (const float*)d_in[8];
    const float* f_conv_w = (const float*)d_in[9];
    const float* f_conv_b = (const float*)d_in[10];
    const float* f_xproj  = (const float*)d_in[11];
    const float* f_dt_w   = (const float*)d_in[12];
    const float* f_dt_b   = (const float*)d_in[13];
    const float* f_A_log  = (const float*)d_in[14];
    const float* f_Dp     = (const float*)d_in[15];
    const float* f_out_w  = (const float*)d_in[16];
    const float* b_in_w   = (const float*)d_in[17];
    const float* b_conv_w = (const float*)d_in[18];
    const float* b_conv_b = (const float*)d_in[19];
    const float* b_xproj  = (const float*)d_in[20];
    const float* b_dt_w   = (const float*)d_in[21];
    const float* b_dt_b   = (const float*)d_in[22];
    const float* b_A_log  = (const float*)d_in[23];
    const float* b_Dp     = (const float*)d_in[24];
    const float* b_out_w  = (const float*)d_in[25];
    float* out = (float*)d_out;

    // ---- workspace layout (float units) ----
    float* ws    = (float*)d_ws;
    bf16_t* xn   = (bf16_t*)ws;                        // 7,077,888 bf16 (3,538,944 fl)
    bf16_t* xz   = (bf16_t*)(ws + 3538944);            // 2 x 14,155,776 bf16 (14,155,776 fl)
    bf16_t* xc   = (bf16_t*)(ws + 17694720);           // 2 x 7,077,888 bf16 (7,077,888 fl)
    bf16_t* dtb  = (bf16_t*)(ws + 24772608);           // 2 x 7,077,888 bf16 (7,077,888 fl)
    float* bc    = ws + 31850496;                      // 2 x 294,912 fl (589,824 fl)
    bf16_t* yb   = (bf16_t*)(ws + 32440320);           // 2 x 7,077,888 bf16 (7,077,888 fl)
    bf16_t* h1   = (bf16_t*)(ws + 39518208);           // 7,077,888 bf16 (3,538,944 fl)
    float* Aprod = ws + 43057152;                      // 2 x 2,359,296 fl
    float* Hend  = ws + 47775744;                      // 2 x 2,359,296 fl
    bf16_t* wbf  = (bf16_t*)(ws + 52494336);           // 7,716,864 bf16 (3,858,432 fl)
    int* rev_f   = (int*)(ws + 56352768);              // 2304
    int* rev_b   = rev_f + 2304;                       // 2304  (end: 56,357,376 fl = 225.4 MB)

    bf16_t* w_fin    = wbf + 0;
    bf16_t* w_bin    = wbf + 1179648;
    bf16_t* w_1      = wbf + 2359296;   // 768 x 1536
    bf16_t* w_2      = wbf + 3538944;   // 768 x 768
    bf16_t* w_fcombo = wbf + 4128768;   // 800 x 768
    bf16_t* w_bcombo = wbf + 4743168;   // 800 x 768
    bf16_t* foutT    = wbf + 5357568;   // 768 x 768 (f_out_w^T)
    bf16_t* boutT    = wbf + 5947392;   // 768 x 768
    bf16_t* Ccat     = wbf + 6537216;   // 768 x 1536 ([W1a@fout | W1b@bout])

    // ---- weight preprocessing ----
    wconv_k<<<16320, 256, 0, stream>>>(f_in_w, b_in_w, fuse_w1, fuse_w2,
                                       f_xproj + 48*768, b_xproj + 48*768, wbf);
    transp_k<<<dim3(24,24,2), 256, 0, stream>>>(f_out_w, b_out_w, foutT, boutT);
    inv_k<<<9, 256, 0, stream>>>(sidx, rev_f, rev_b);
    combo_k<<<768, 256, 0, stream>>>(f_dt_w, f_xproj, w_fcombo);
    combo_k<<<768, 256, 0, stream>>>(b_dt_w, b_xproj, w_bcombo);
    ln_k<<<MTOK, 256, 0, stream>>>(x, norm_g, norm_b, xn);
    // Ccat: dir0: Cf[n][d] = sum_c W1[n][c]*foutT[d][c]; dir1 same with +768 col offset
    gemm4_k<0,0,2><<<dim3(6,6,2), 256, 0, stream>>>(
        w_1, 768, 1536, foutT, boutT, 768, 768,
        Ccat, 0, nullptr, 0, 1536, 768, nullptr, nullptr, nullptr, nullptr,
        nullptr, nullptr);

    const unsigned lds1 = 18432, lds3 = 30720;

    // ---- in-projection (both dirs) ----
    gemm4_k<3,0,2><<<dim3(72,12,2), 256, 0, stream>>>(
        xn, 0, CC, w_fin, w_bin, 1536, 768,
        xz, S_XZ, nullptr, 0, 1536, 0, nullptr, nullptr, nullptr, sidx,
        nullptr, nullptr);
    // ---- depthwise conv (both dirs) ----
    conv_k<<<dim3(27648,2), 256, 0, stream>>>(xz, f_conv_w, b_conv_w,
                                              f_conv_b, b_conv_b, xc);
    // ---- combo projection: softplus(dt) + B/C (both dirs) ----
    gemm4_k<0,0,5><<<dim3(72,7,2), 256, 0, stream>>>(
        xc, S_XC, DINNER, w_fcombo, w_bcombo, 800, 768,
        dtb, S_DT, bc, S_BC, 768, 0, f_dt_b, b_dt_b, nullptr, nullptr,
        nullptr, nullptr);
    // ---- selective scan (both dirs) ----
    scanp_k<1><<<dim3(BB*NCH*12,2), 256, lds1, stream>>>(
        dtb, xc, bc, nullptr, f_A_log, b_A_log, f_Dp, b_Dp, Aprod, Hend, nullptr);
    scan2_k<<<384, 256, 0, stream>>>(Aprod, Hend);
    scanp_k<3><<<dim3(BB*NCH*12,2), 256, lds3, stream>>>(
        dtb, xc, bc, xz, f_A_log, b_A_log, f_Dp, b_Dp, Aprod, Hend, yb);
    // ---- fused out-proj + fuse1: h1 = gelu(yf[rev_f]@Cf^T + yb[rev_b]@Cb^T + b1) ----
    gemm4_k<4,0,3><<<dim3(72,6,1), 256, 0, stream>>>(
        yb, S_YB, DINNER, Ccat, Ccat, 768, 1536,
        h1, 0, nullptr, 0, 768, 0, fuse_b1, fuse_b1, nullptr, nullptr,
        rev_f, rev_b);
    // ---- fuse2 + residual ----
    gemm4_k<0,0,4><<<dim3(72,6,1), 256, 0, stream>>>(
        h1, 0, DINNER, w_2, w_2, 768, 768,
        out, 0, nullptr, 0, 768, 0, fuse_b2, fuse_b2, x, nullptr,
        nullptr, nullptr);
}

// Round 8
// 609.744 us; speedup vs baseline: 2.6236x; 1.0371x over previous
//
#include <hip/hip_runtime.h>
#include <hip/hip_bf16.h>
#include <cmath>

#define BB 4
#define LL 2304
#define CC 768
#define DSTATE 16
#define DINNER 768
#define DTRANK 48
#define MTOK (BB*LL)          // 9216
#define NCH 48
#define LCH (LL/NCH)          // 48

// per-direction strides (element units)
#define S_XZ   14155776L
#define S_XC   7077888L
#define S_DT   7077888L
#define S_BC   294912L
#define S_YB   7077888L
#define S_AP   2359296L

typedef __bf16 bf16_t;
typedef __bf16 bf16x8 __attribute__((ext_vector_type(8)));
typedef float  f32x4  __attribute__((ext_vector_type(4)));

__device__ __forceinline__ float silu_f(float v){ return v / (1.0f + __expf(-v)); }
// fast softplus: exact form max(v,0)+log1p(exp(-|v|)); log1p replaced by __logf
// (arg in (1,2], rel err ~1e-7 — far below bf16 storage rounding)
__device__ __forceinline__ float softplus_f(float v){
    return fmaxf(v,0.f) + __logf(1.0f + __expf(-fabsf(v)));
}

typedef __attribute__((address_space(3))) void  lds_vt;
typedef __attribute__((address_space(1))) void  gbl_vt;
__device__ __forceinline__ void async_copy16(const void* g, void* l){
    __builtin_amdgcn_global_load_lds((const gbl_vt*)g, (lds_vt*)l, 16, 0, 0);
}

// ---------------- weight fp32 -> bf16 conversion ----------------------------
// segments: f_in, b_in, fuse_w1, fuse_w2, f_bc(xproj rows 48..79), b_bc
__global__ __launch_bounds__(256)
void wconv_k(const float* __restrict__ a0, const float* __restrict__ a1,
             const float* __restrict__ a2, const float* __restrict__ a3,
             const float* __restrict__ a4, const float* __restrict__ a5,
             bf16_t* __restrict__ dst)
{
    const int cum[7]  = {0,1179648,2359296,3538944,4128768,4153344,4177920};
    const int dofs[6] = {0,1179648,2359296,3538944,4718592,5332992};
    const float* srcs[6] = {a0,a1,a2,a3,a4,a5};
    int idx = blockIdx.x*256 + threadIdx.x;
    if (idx >= 4177920) return;
    int seg = 0;
    while (idx >= cum[seg+1]) ++seg;
    dst[dofs[seg] + idx - cum[seg]] = (bf16_t)srcs[seg][idx - cum[seg]];
}

// ---------------- transpose+convert 768x768 fp32 -> bf16 (dst = src^T) ------
__global__ __launch_bounds__(256)
void transp_k(const float* __restrict__ s0, const float* __restrict__ s1,
              bf16_t* __restrict__ d0, bf16_t* __restrict__ d1)
{
    __shared__ float tile[32][33];
    const float* src = blockIdx.z ? s1 : s0;
    bf16_t* dst = blockIdx.z ? d1 : d0;
    int c0 = blockIdx.y*32, d0c = blockIdx.x*32;
    int tx = threadIdx.x & 31, ty = threadIdx.x >> 5;   // ty 0..7
#pragma unroll
    for (int r=0;r<4;++r)
        tile[ty+8*r][tx] = src[(long)(c0+ty+8*r)*768 + d0c+tx];
    __syncthreads();
#pragma unroll
    for (int r=0;r<4;++r)
        dst[(long)(d0c+ty+8*r)*768 + c0+tx] = (bf16_t)tile[tx][ty+8*r];
}

// ---------------- inverse permutations ---------------------------------------
__global__ __launch_bounds__(256)
void inv_k(const int* __restrict__ sidx, int* __restrict__ rf, int* __restrict__ rb)
{
    int t = blockIdx.x*256 + threadIdx.x;
    if (t >= LL) return;
    rf[sidx[t]] = t;
    rb[sidx[LL-1-t]] = t;
}

// ---------------- combo weight: dst[n*768+k] = sum_r dtw[n*48+r]*xproj[r*768+k]
__global__ __launch_bounds__(256)
void combo_k(const float* __restrict__ dtw, const float* __restrict__ xproj,
             bf16_t* __restrict__ dst)
{
    __shared__ float row[48];
    int n = blockIdx.x;
    if (threadIdx.x < 48) row[threadIdx.x] = dtw[n*48 + threadIdx.x];
    __syncthreads();
#pragma unroll
    for (int kk=0; kk<3; ++kk){
        int k = threadIdx.x + 256*kk;
        float s = 0.f;
#pragma unroll 8
        for (int r=0; r<48; ++r) s += row[r]*xproj[r*768 + k];
        dst[n*768 + k] = (bf16_t)s;
    }
}

// ---------------- LayerNorm (per token, C=768) -> bf16 ----------------------
__global__ __launch_bounds__(256)
void ln_k(const float* __restrict__ x, const float* __restrict__ g,
          const float* __restrict__ bta, bf16_t* __restrict__ xn)
{
    int row = blockIdx.x;
    const float* xr = x + (long)row*CC;
    int tid = threadIdx.x;
    float v[3];
#pragma unroll
    for (int r=0;r<3;++r) v[r] = xr[tid + 256*r];
    float s  = v[0]+v[1]+v[2];
    float s2 = v[0]*v[0]+v[1]*v[1]+v[2]*v[2];
    __shared__ float red[8];
    for (int o=32;o;o>>=1){ s += __shfl_down(s,o); s2 += __shfl_down(s2,o); }
    int wv = tid>>6, ln = tid&63;
    if (ln==0){ red[wv]=s; red[4+wv]=s2; }
    __syncthreads();
    if (tid==0){
        red[0] = red[0]+red[1]+red[2]+red[3];
        red[4] = red[4]+red[5]+red[6]+red[7];
    }
    __syncthreads();
    float mu  = red[0]*(1.0f/CC);
    float var = red[4]*(1.0f/CC) - mu*mu;
    float rstd = rsqrtf(var + 1e-6f);
#pragma unroll
    for (int r=0;r<3;++r){
        int c = tid + 256*r;
        xn[(long)row*CC + c] = (bf16_t)((v[r]-mu)*rstd*g[c] + bta[c]);
    }
}

// ---------------- depthwise causal conv (k=4) + silu, vectorized x8 ---------
__global__ __launch_bounds__(256)
void conv_k(const bf16_t* __restrict__ xz, const float* __restrict__ cw0,
            const float* __restrict__ cw1, const float* __restrict__ cb0,
            const float* __restrict__ cb1, bf16_t* __restrict__ xc)
{
    int dir = blockIdx.y;
    const bf16_t* xzd = xz + (long)dir*S_XZ;
    const float* cw = dir ? cw1 : cw0;
    const float* cb = dir ? cb1 : cb0;
    bf16_t* xcd = xc + (long)dir*S_XC;
    int idx = blockIdx.x*256 + threadIdx.x;     // over MTOK*96 groups of 8
    if (idx >= MTOK*(DINNER/8)) return;
    int dg = idx % (DINNER/8);
    int row = idx / (DINNER/8);
    int d0 = dg*8;
    int t = row % LL; int b4 = row - t;
    float acc[8];
#pragma unroll
    for (int u=0;u<8;++u) acc[u] = cb[d0+u];
#pragma unroll
    for (int k=0;k<4;++k){
        int tt = t - 3 + k;
        if (tt >= 0){
            bf16x8 v = *(const bf16x8*)&xzd[(long)(b4+tt)*1536 + d0];
#pragma unroll
            for (int u=0;u<8;++u) acc[u] += cw[(d0+u)*4 + k] * (float)v[u];
        }
    }
    bf16x8 o;
#pragma unroll
    for (int u=0;u<8;++u) o[u] = (bf16_t)silu_f(acc[u]);
    *(bf16x8*)&xcd[(long)row*DINNER + d0] = o;
}

// ---------------- GEMM4: LDS-staged MFMA GEMM, 128x128 tile, BK=64 ----------
// Grid: x = m-tile (XCD locality), y = n-tile, z = dir.
// GATHER: 0 none, 3 runtime-dir (dir0: sidx[t], dir1: sidx[LL-1-t]),
//         4 dual-phase A (k<768: A row bo+ridx0[t]; k>=768: A+a_stride row bo+ridx1[t])
// SCATTER: 0 none, 3 runtime-dir
// EPI: 2 store bf16 (staged wide) | 3 gelu+bias->bf16 (staged) |
//      4 bias+resid->f32 scalar | 5 combo: softplus->bf16 staged (n0<768),
//        B/C cols ->f32 scalar (n0>=768)
template<int GATHER, int SCATTER, int EPI>
__global__ __launch_bounds__(256)
void gemm4_k(const bf16_t* __restrict__ A, long a_stride, int lda,
             const bf16_t* __restrict__ W0, const bf16_t* __restrict__ W1,
             int N, int K,
             void* __restrict__ out1, long o1_stride,
             void* __restrict__ out2, long o2_stride,
             int ldc, int ccol_stride,
             const float* __restrict__ bias0, const float* __restrict__ bias1,
             const float* __restrict__ resid,
             const int* __restrict__ sidx,
             const int* __restrict__ ridx0, const int* __restrict__ ridx1)
{
    __shared__ __align__(16) bf16_t smem[2*128*64];   // As | Bs ; reused as Cs
    bf16_t* As = smem;
    bf16_t* Bs = smem + 128*64;

    const int tid  = threadIdx.x;
    const int lane = tid & 63;
    const int w    = tid >> 6;
    const int ln16 = lane & 15;
    const int q    = lane >> 4;
    const int dir  = blockIdx.z;

    const bf16_t* Ad = A + (long)dir*a_stride;
    const bf16_t* W  = dir ? W1 : W0;
    const float* bias = dir ? bias1 : bias0;

    const int m0 = blockIdx.x*128;
    const int n0 = blockIdx.y*128;

    const int srow = lane >> 3;
    const int csrc = (lane & 7) ^ srow;
    const bf16_t* gA[4]; const bf16_t* gA1[4]; const bf16_t* gB[4];
#pragma unroll
    for (int inst=0; inst<4; ++inst){
        int row = w*32 + inst*8 + srow;
        int r = m0 + row;
        if (GATHER == 4){
            int t = r % LL; int bo = r - t;
            gA[inst]  = A + (long)(bo + ridx0[t])*lda + csrc*8;
            gA1[inst] = A + a_stride + (long)(bo + ridx1[t])*lda + csrc*8;
        } else {
            int sr = r;
            if (GATHER == 3){
                int t = r % LL; int bo = r - t;
                sr = bo + (dir ? sidx[LL-1-t] : sidx[t]);
            }
            gA[inst] = Ad + (long)sr*lda + csrc*8;
        }
        int n = n0 + row; if (n >= N) n = N-1;
        gB[inst] = W + (long)n*K + csrc*8;
    }

    f32x4 acc[4][4];
#pragma unroll
    for (int i=0;i<4;++i)
#pragma unroll
      for (int j=0;j<4;++j) acc[i][j] = (f32x4){0.f,0.f,0.f,0.f};

    const int e = ln16 & 7;
    const int ar_base = ((w>>1)*64 + ln16)*64;
    const int br_base = ((w&1)*64 + ln16)*64;

    for (int k0 = 0; k0 < K; k0 += 64){
#pragma unroll
        for (int inst=0; inst<4; ++inst){
            bf16_t* la = As + (w*256 + inst*64)*8;
            bf16_t* lb = Bs + (w*256 + inst*64)*8;
            const bf16_t* asrc;
            if (GATHER == 4)
                asrc = (k0 >= 768) ? (gA1[inst] + (k0 - 768)) : (gA[inst] + k0);
            else
                asrc = gA[inst] + k0;
            async_copy16(asrc, la);
            async_copy16(gB[inst] + k0, lb);
        }
        __syncthreads();
#pragma unroll
        for (int kk=0; kk<2; ++kk){
            const int ce = (((kk<<2)|q) ^ e)*8;
            bf16x8 af[4], bf[4];
#pragma unroll
            for (int i=0;i<4;++i) af[i] = *(const bf16x8*)&As[ar_base + i*16*64 + ce];
#pragma unroll
            for (int j=0;j<4;++j) bf[j] = *(const bf16x8*)&Bs[br_base + j*16*64 + ce];
#pragma unroll
            for (int i=0;i<4;++i)
#pragma unroll
              for (int j=0;j<4;++j)
                acc[i][j] = __builtin_amdgcn_mfma_f32_16x16x32_bf16(af[i], bf[j], acc[i][j], 0,0,0);
        }
        __syncthreads();
    }

    const int mw = (w>>1)*64;
    const int nw = (w&1)*64;
    const int ccolb = ccol_stride*dir;

    const bool staged = (EPI==2) || (EPI==3) || (EPI==5 && n0 < 768);
    if (staged){
        // ---- LDS-transposed epilogue: stage C tile (128x128 bf16 = 32KB) ----
        bf16_t* Cs = smem;
#pragma unroll
        for (int i=0;i<4;++i){
#pragma unroll
            for (int reg=0; reg<4; ++reg){
                int rowl = mw + i*16 + q*4 + reg;
#pragma unroll
                for (int j=0;j<4;++j){
                    int coll = nw + j*16 + ln16;
                    float v = acc[i][j][reg];
                    if (EPI==3){
                        v += bias[n0 + coll];
                        v = 0.5f*v*(1.0f + erff(v*0.70710678118654752f));
                    } else if (EPI==5){
                        v = softplus_f(v + bias[n0 + coll]);
                    }
                    Cs[rowl*128 + coll] = (bf16_t)v;
                }
            }
        }
        __syncthreads();
        bf16_t* o = (bf16_t*)out1 + (long)dir*o1_stride;
#pragma unroll
        for (int c=0;c<8;++c){
            int chunk = tid + 256*c;            // 0..2047
            int rowl = chunk >> 4;
            int coll = (chunk & 15)*8;
            int r = m0 + rowl;
            int orow = r;
            if (SCATTER == 3){
                int t = r % LL; int bo = r - t;
                orow = bo + (dir ? sidx[LL-1-t] : sidx[t]);
            }
            *(int4*)&o[(long)orow*ldc + ccolb + n0 + coll] = *(const int4*)&Cs[rowl*128 + coll];
        }
    } else {
        // ---- scalar epilogue (EPI 4, or EPI 5 bc-tile) ----
#pragma unroll
        for (int i=0;i<4;++i){
#pragma unroll
            for (int reg=0; reg<4; ++reg){
                int r = m0 + mw + i*16 + q*4 + reg;
#pragma unroll
                for (int j=0;j<4;++j){
                    int col = n0 + nw + j*16 + ln16;
                    if (col >= N) continue;
                    float v = acc[i][j][reg];
                    if (EPI==4){
                        v += bias[col] + resid[(long)r*CC + col];
                        ((float*)out1)[(long)r*ldc + col] = v;
                    } else { // EPI==5 bc tile (col in [768, 800))
                        ((float*)out2 + (long)dir*o2_stride)[(long)r*32 + (col-768)] = v;
                    }
                }
            }
        }
    }
}

// ---------------- LDS-staged chunked selective scan (dir-fused) -------------
template<int PASS>
__global__ __launch_bounds__(256)
void scanp_k(const bf16_t* __restrict__ dtp, const bf16_t* __restrict__ xcp,
             const float* __restrict__ bcp, const bf16_t* __restrict__ xzp,
             const float* __restrict__ Al0, const float* __restrict__ Al1,
             const float* __restrict__ Dp0, const float* __restrict__ Dp1,
             float* __restrict__ Aprod, float* __restrict__ Hend,
             bf16_t* __restrict__ yout)
{
    extern __shared__ __align__(16) char smem[];
    bf16_t* s_dt = (bf16_t*)smem;            // 6144 B
    bf16_t* s_xc = (bf16_t*)(smem + 6144);   // 6144 B
    float*  s_bc = (float*) (smem + 12288);  // 6144 B
    bf16_t* s_z  = (bf16_t*)(smem + 18432);  // 6144 B (PASS 3)
    bf16_t* s_y  = (bf16_t*)(smem + 24576);  // 6144 B (PASS 3)

    int dir = blockIdx.y;
    int blk = blockIdx.x;
    int dblk = blk % 12; int tmp = blk / 12;
    int j = tmp % NCH; int b = tmp / NCH;
    int tid = threadIdx.x;
    long tbase = (long)b*LL + (long)j*LCH;

    const bf16_t* gdt = dtp + dir*S_DT + tbase*DINNER + dblk*64;
    const bf16_t* gxc = xcp + dir*S_XC + tbase*DINNER + dblk*64;
    const float*  gbc = bcp + dir*S_BC + tbase*32;
    {
        int c = tid, t = c>>3, dc = c&7;
        async_copy16(gdt + (long)t*DINNER + dc*8, s_dt + c*8);
        async_copy16(gxc + (long)t*DINNER + dc*8, s_xc + c*8);
        async_copy16(gbc + (long)t*32 + dc*4, s_bc + c*4);
        if (tid < 128){
            c = tid + 256; t = c>>3; dc = c&7;
            async_copy16(gdt + (long)t*DINNER + dc*8, s_dt + c*8);
            async_copy16(gxc + (long)t*DINNER + dc*8, s_xc + c*8);
            async_copy16(gbc + (long)t*32 + dc*4, s_bc + c*4);
        }
    }
    if (PASS==3){
        const bf16_t* gz = xzp + dir*S_XZ + tbase*1536 + DINNER + dblk*64;
        int c = tid, t = c>>3, dc = c&7;
        async_copy16(gz + (long)t*1536 + dc*8, s_z + c*8);
        if (tid < 128){ c = tid+256; t = c>>3; dc = c&7;
            async_copy16(gz + (long)t*1536 + dc*8, s_z + c*8); }
    }
    __syncthreads();

    int lane = tid & 63, w = tid >> 6;
    int d_low = lane & 15, sg = lane >> 4;
    int dl = w*16 + d_low;
    int d  = dblk*64 + dl;

    const float* Al = dir ? Al1 : Al0;
    f32x4 al = *(const f32x4*)&Al[d*DSTATE + sg*4];
    float a_c[4];
#pragma unroll
    for (int k=0;k<4;++k) a_c[k] = -__expf(al[k]);

    float h[4] = {0.f,0.f,0.f,0.f};
    float dpv = 0.f;
    long o = dir*S_AP + ((long)(b*NCH + j)*DINNER + d)*DSTATE + sg*4;
    if (PASS==3){
        f32x4 hin = *(const f32x4*)&Aprod[o];   // carries written in place
#pragma unroll
        for (int k=0;k<4;++k) h[k] = hin[k];
        dpv = (dir ? Dp1 : Dp0)[d];
    }
    float sdt = 0.f;

    for (int t=0; t<LCH; ++t){
        float dt = (float)s_dt[t*64 + dl];
        float xv = (float)s_xc[t*64 + dl];
        f32x4 Bv = *(const f32x4*)&s_bc[t*32 + sg*4];
        float c = dt*xv;
        if (PASS==1) sdt += dt;
#pragma unroll
        for (int k=0;k<4;++k){
            float da = __expf(dt * a_c[k]);
            h[k] = da*h[k] + c*Bv[k];
        }
        if (PASS==3){
            f32x4 Cv = *(const f32x4*)&s_bc[t*32 + 16 + sg*4];
            float p = h[0]*Cv[0] + h[1]*Cv[1] + h[2]*Cv[2] + h[3]*Cv[3];
            p += __shfl_xor(p, 16);
            p += __shfl_xor(p, 32);
            if (sg == 0){
                float z = (float)s_z[t*64 + dl];
                s_y[t*64 + dl] = (bf16_t)((p + dpv*xv) * silu_f(z));
            }
        }
    }

    if (PASS==1){
        f32x4 ap, hv;
#pragma unroll
        for (int k=0;k<4;++k){ ap[k] = __expf(sdt * a_c[k]); hv[k] = h[k]; }
        *(f32x4*)&Aprod[o] = ap;
        *(f32x4*)&Hend[o]  = hv;
    }
    if (PASS==3){
        __syncthreads();
        bf16_t* gy = yout + dir*S_YB + tbase*DINNER + dblk*64;
        int c = tid, t = c>>3, dc = c&7;
        *(int4*)(gy + (long)t*DINNER + dc*8) = *(const int4*)&s_y[c*8];
        if (tid < 128){ c = tid+256; t = c>>3; dc = c&7;
            *(int4*)(gy + (long)t*DINNER + dc*8) = *(const int4*)&s_y[c*8]; }
    }
}

// pass2: sequential combine (both dirs); carry-in written IN PLACE into Aprod
__global__ __launch_bounds__(256)
void scan2_k(float* __restrict__ Aprod, const float* __restrict__ Hend)
{
    int idx = blockIdx.x*256 + threadIdx.x;
    if (idx >= 2*BB*DINNER*DSTATE) return;
    int dir = idx / (BB*DINNER*DSTATE);
    int rem = idx - dir*(BB*DINNER*DSTATE);
    int b = rem / (DINNER*DSTATE);
    int ds = rem % (DINNER*DSTATE);
    long base = (long)dir*S_AP;
    float h = 0.f;
    for (int j=0;j<NCH;++j){
        long o = base + (long)(b*NCH+j)*DINNER*DSTATE + ds;
        float ap = Aprod[o];
        float he = Hend[o];
        Aprod[o] = h;
        h = ap*h + he;
    }
}

// ----------------------------------------------------------------------------
extern "C" void kernel_launch(void* const* d_in, const int* in_sizes, int n_in,
                              void* d_out, int out_size, void* d_ws, size_t ws_size,
                              hipStream_t stream)
{
    const float* x       = (const float*)d_in[0];
    const int*   sidx    = (const int*)  d_in[1];
    const float* norm_g  = (const float*)d_in[2];
    const float* norm_b  = (const float*)d_in[3];
    const float* fuse_w1 = (const float*)d_in[4];
    const float* fuse_b1 = (const float*)d_in[5];
    const float* fuse_w2 = (const float*)d_in[6];
    const float* fuse_b2 = (const float*)d_in[7];
    const float* f_in_w   = (const float*)d_in[8];
    const float* f_conv_w = (const float*)d_in[9];
    const float* f_conv_b = (const float*)d_in[10];
    const float* f_xproj  = (const float*)d_in[11];
    const float* f_dt_w   = (const float*)d_in[12];
    const float* f_dt_b   = (const float*)d_in[13];
    const float* f_A_log  = (const float*)d_in[14];
    const float* f_Dp     = (const float*)d_in[15];
    const float* f_out_w  = (const float*)d_in[16];
    const float* b_in_w   = (const float*)d_in[17];
    const float* b_conv_w = (const float*)d_in[18];
    const float* b_conv_b = (const float*)d_in[19];
    const float* b_xproj  = (const float*)d_in[20];
    const float* b_dt_w   = (const float*)d_in[21];
    const float* b_dt_b   = (const float*)d_in[22];
    const float* b_A_log  = (const float*)d_in[23];
    const float* b_Dp     = (const float*)d_in[24];
    const float* b_out_w  = (const float*)d_in[25];
    float* out = (float*)d_out;

    // ---- workspace layout (float units) ----
    float* ws    = (float*)d_ws;
    bf16_t* xn   = (bf16_t*)ws;                        // 7,077,888 bf16
    bf16_t* xz   = (bf16_t*)(ws + 3538944);            // 2 x 14,155,776 bf16
    bf16_t* xc   = (bf16_t*)(ws + 17694720);           // 2 x 7,077,888 bf16
    bf16_t* dtb  = (bf16_t*)(ws + 24772608);           // 2 x 7,077,888 bf16
    float* bc    = ws + 31850496;                      // 2 x 294,912 fl
    bf16_t* yb   = (bf16_t*)(ws + 32440320);           // 2 x 7,077,888 bf16
    bf16_t* h1   = (bf16_t*)(ws + 39518208);           // 7,077,888 bf16
    float* Aprod = ws + 43057152;                      // 2 x 2,359,296 fl
    float* Hend  = ws + 47775744;                      // 2 x 2,359,296 fl
    bf16_t* wbf  = (bf16_t*)(ws + 52494336);           // 7,716,864 bf16
    int* rev_f   = (int*)(ws + 56352768);              // 2304
    int* rev_b   = rev_f + 2304;                       // 2304

    bf16_t* w_fin    = wbf + 0;
    bf16_t* w_bin    = wbf + 1179648;
    bf16_t* w_1      = wbf + 2359296;   // 768 x 1536
    bf16_t* w_2      = wbf + 3538944;   // 768 x 768
    bf16_t* w_fcombo = wbf + 4128768;   // 800 x 768
    bf16_t* w_bcombo = wbf + 4743168;   // 800 x 768
    bf16_t* foutT    = wbf + 5357568;   // 768 x 768 (f_out_w^T)
    bf16_t* boutT    = wbf + 5947392;   // 768 x 768
    bf16_t* Ccat     = wbf + 6537216;   // 768 x 1536 ([W1a@fout | W1b@bout])

    // ---- weight preprocessing ----
    wconv_k<<<16320, 256, 0, stream>>>(f_in_w, b_in_w, fuse_w1, fuse_w2,
                                       f_xproj + 48*768, b_xproj + 48*768, wbf);
    transp_k<<<dim3(24,24,2), 256, 0, stream>>>(f_out_w, b_out_w, foutT, boutT);
    inv_k<<<9, 256, 0, stream>>>(sidx, rev_f, rev_b);
    combo_k<<<768, 256, 0, stream>>>(f_dt_w, f_xproj, w_fcombo);
    combo_k<<<768, 256, 0, stream>>>(b_dt_w, b_xproj, w_bcombo);
    ln_k<<<MTOK, 256, 0, stream>>>(x, norm_g, norm_b, xn);
    // Ccat: dir0: Cf[n][d] = sum_c W1[n][c]*foutT[d][c]; dir1 +768 col offset
    gemm4_k<0,0,2><<<dim3(6,6,2), 256, 0, stream>>>(
        w_1, 768, 1536, foutT, boutT, 768, 768,
        Ccat, 0, nullptr, 0, 1536, 768, nullptr, nullptr, nullptr, nullptr,
        nullptr, nullptr);

    const unsigned lds1 = 18432, lds3 = 30720;

    // ---- in-projection (both dirs) ----
    gemm4_k<3,0,2><<<dim3(72,12,2), 256, 0, stream>>>(
        xn, 0, CC, w_fin, w_bin, 1536, 768,
        xz, S_XZ, nullptr, 0, 1536, 0, nullptr, nullptr, nullptr, sidx,
        nullptr, nullptr);
    // ---- depthwise conv (both dirs, x8 vectorized) ----
    conv_k<<<dim3(3456,2), 256, 0, stream>>>(xz, f_conv_w, b_conv_w,
                                             f_conv_b, b_conv_b, xc);
    // ---- combo projection: softplus(dt) + B/C (both dirs) ----
    gemm4_k<0,0,5><<<dim3(72,7,2), 256, 0, stream>>>(
        xc, S_XC, DINNER, w_fcombo, w_bcombo, 800, 768,
        dtb, S_DT, bc, S_BC, 768, 0, f_dt_b, b_dt_b, nullptr, nullptr,
        nullptr, nullptr);
    // ---- selective scan (both dirs) ----
    scanp_k<1><<<dim3(BB*NCH*12,2), 256, lds1, stream>>>(
        dtb, xc, bc, nullptr, f_A_log, b_A_log, f_Dp, b_Dp, Aprod, Hend, nullptr);
    scan2_k<<<384, 256, 0, stream>>>(Aprod, Hend);
    scanp_k<3><<<dim3(BB*NCH*12,2), 256, lds3, stream>>>(
        dtb, xc, bc, xz, f_A_log, b_A_log, f_Dp, b_Dp, Aprod, Hend, yb);
    // ---- fused out-proj + fuse1: h1 = gelu(yf[rev_f]@Cf^T + yb[rev_b]@Cb^T + b1) ----
    gemm4_k<4,0,3><<<dim3(72,6,1), 256, 0, stream>>>(
        yb, S_YB, DINNER, Ccat, Ccat, 768, 1536,
        h1, 0, nullptr, 0, 768, 0, fuse_b1, fuse_b1, nullptr, nullptr,
        rev_f, rev_b);
    // ---- fuse2 + residual ----
    gemm4_k<0,0,4><<<dim3(72,6,1), 256, 0, stream>>>(
        h1, 0, DINNER, w_2, w_2, 768, 768,
        out, 0, nullptr, 0, 768, 0, fuse_b2, fuse_b2, x, nullptr,
        nullptr, nullptr);
}